// Round 2
// baseline (6321.041 us; speedup 1.0000x reference)
//
#include <hip/hip_runtime.h>
#include <hip/hip_bf16.h>

#define DEV __device__ __forceinline__

DEV float bf2f(unsigned short u){ return __uint_as_float(((unsigned)u)<<16); }
DEV unsigned short f2bf(float f){
  unsigned u = __float_as_uint(f);
  u += 0x7fffu + ((u>>16)&1u);   // RNE
  return (unsigned short)(u>>16);
}

// ---------------------------------------------------------------------------
// dtype detection: genuine bf16 N(0,1) data never has exponent >= 0xC0
// (|v| >= 2^65); an fp32 buffer read as ushorts has ~25% such halfwords
// (random mantissa bits land in the exponent field). flag=1 -> inputs fp32.
__global__ __launch_bounds__(256) void detect_kernel(
    const unsigned short* __restrict__ x, int* __restrict__ flag){
  __shared__ int cnt;
  if (threadIdx.x==0) cnt = 0;
  __syncthreads();
  int local = 0;
  for (int i=threadIdx.x; i<4096; i+=256){
    int e = (x[i]>>7)&0xFF;
    if (e >= 0xC0) local++;
  }
  atomicAdd(&cnt, local);
  __syncthreads();
  if (threadIdx.x==0) *flag = (cnt > 64) ? 1 : 0;
}

// ---------------------------------------------------------------------------
// canonicalize the 14 parameter tensors to fp32 (either upcast bf16 or copy).
struct PConv {
  const void* s[14];
  float*      d[14];
  int         sz[14];
};
__global__ __launch_bounds__(256) void conv_params_kernel(PConv p, const int* __restrict__ flag){
  bool isf = (*flag != 0);
  int i = blockIdx.x*256 + threadIdx.x;
  int seg = 0, off = i;
  #pragma unroll
  for (seg=0; seg<14; ++seg){
    if (off < p.sz[seg]) break;
    off -= p.sz[seg];
  }
  if (seg >= 14) return;
  float v = isf ? ((const float*)p.s[seg])[off]
                : bf2f(((const unsigned short*)p.s[seg])[off]);
  p.d[seg][off] = v;
}

// ---------------------------------------------------------------------------
// prep: upcast coords (B,3,2048)->(B,2048,3) fp32, f0 = w_in@x + b_in (B,2048,8),
// zero the 4 layers' group-norm stat accumulators (1024 floats).
__global__ __launch_bounds__(256) void prep_kernel(
    const void* __restrict__ xraw, const int* __restrict__ flag,
    const float* __restrict__ w_in, const float* __restrict__ b_in,
    float* __restrict__ xyz0, float* __restrict__ f0, float* __restrict__ stats){
  int i = blockIdx.x*256 + threadIdx.x;          // 32*2048 threads
  if (i < 1024) stats[i] = 0.f;
  bool isf = (*flag != 0);
  int b = i >> 11, n = i & 2047;
  size_t base = (size_t)b*3*2048 + n;
  float X, Y, Z;
  if (isf){
    const float* xf = (const float*)xraw;
    X = xf[base]; Y = xf[base+2048]; Z = xf[base+4096];
  } else {
    const unsigned short* xu = (const unsigned short*)xraw;
    X = bf2f(xu[base]); Y = bf2f(xu[base+2048]); Z = bf2f(xu[base+4096]);
  }
  float* o3 = xyz0 + (size_t)i*3;
  o3[0]=X; o3[1]=Y; o3[2]=Z;
  float* fo = f0 + (size_t)i*8;
  #pragma unroll
  for (int o=0;o<8;++o){
    fo[o] = w_in[o*3+0]*X + w_in[o*3+1]*Y + w_in[o*3+2]*Z + b_in[o];
  }
}

// ---------------------------------------------------------------------------
// kNN: per query the 16 smallest dists (ties -> lower index), exact fp32 no-FMA
// replication of ref: dist = (sq_q + sq_k) - 2*dot.
template<int NK>
__global__ __launch_bounds__(256) void knn_kernel(
    const float* __restrict__ qxyz, const float* __restrict__ kxyz,
    int Nq, int* __restrict__ oidx){
  __shared__ float kx[NK], ky[NK], kz[NK], sk[NK];
  int b = blockIdx.y, t = threadIdx.x;
  for (int i=t; i<NK; i+=256){
    const float* p = kxyz + ((size_t)b*NK + i)*3;
    float X=p[0], Y=p[1], Z=p[2];
    kx[i]=X; ky[i]=Y; kz[i]=Z;
    sk[i] = __fadd_rn(__fadd_rn(__fmul_rn(X,X),__fmul_rn(Y,Y)),__fmul_rn(Z,Z));
  }
  __syncthreads();
  int q = blockIdx.x*256 + t;
  if (q >= Nq) return;
  const float* qp = qxyz + ((size_t)b*Nq + q)*3;
  float QX=qp[0], QY=qp[1], QZ=qp[2];
  float sq = __fadd_rn(__fadd_rn(__fmul_rn(QX,QX),__fmul_rn(QY,QY)),__fmul_rn(QZ,QZ));
  float dl[16]; int il[16];
  #pragma unroll
  for (int j=0;j<16;++j){ dl[j]=3.4e38f; il[j]=-1; }
  for (int m=0;m<NK;++m){
    float dot = __fadd_rn(__fadd_rn(__fmul_rn(QX,kx[m]),__fmul_rn(QY,ky[m])),__fmul_rn(QZ,kz[m]));
    float d = __fsub_rn(__fadd_rn(sq, sk[m]), __fmul_rn(2.0f,dot));
    if (d < dl[15]){                    // strict <: equal dist keeps earlier index
      dl[15]=d; il[15]=m;
      #pragma unroll
      for (int j=15;j>0;--j){
        if (dl[j] < dl[j-1]){          // strict <: stable among equals
          float td=dl[j]; dl[j]=dl[j-1]; dl[j-1]=td;
          int   ti=il[j]; il[j]=il[j-1]; il[j-1]=ti;
        }
      }
    }
  }
  int* op = oidx + ((size_t)b*Nq + q)*16;
  #pragma unroll
  for (int j=0;j<16;++j) op[j]=il[j];
}

// ---------------------------------------------------------------------------
// FPS: exact fp32 no-FMA replication; argmax after min-update, first-index ties.
template<int NP, int G>
__global__ __launch_bounds__(512) void fps_kernel(
    const float* __restrict__ xyz, int* __restrict__ oidx, float* __restrict__ oxyz){
  constexpr int PPT = NP/512;
  __shared__ float xl[NP*3];
  __shared__ float cent[3];
  __shared__ float redv[8];
  __shared__ int   redi[8];
  int b = blockIdx.x, t = threadIdx.x;
  for (int i=t;i<NP;i+=512){
    const float* p = xyz + ((size_t)b*NP + i)*3;
    xl[i*3+0]=p[0]; xl[i*3+1]=p[1]; xl[i*3+2]=p[2];
  }
  __syncthreads();
  float px[PPT], py[PPT], pz[PPT], dist[PPT];
  #pragma unroll
  for (int i=0;i<PPT;++i){
    int gi = t + i*512;
    px[i]=xl[gi*3]; py[i]=xl[gi*3+1]; pz[i]=xl[gi*3+2];
    dist[i]=1e10f;
  }
  if (t==0){
    oidx[(size_t)b*G] = 0;
    oxyz[(size_t)b*G*3+0]=xl[0]; oxyz[(size_t)b*G*3+1]=xl[1]; oxyz[(size_t)b*G*3+2]=xl[2];
    cent[0]=xl[0]; cent[1]=xl[1]; cent[2]=xl[2];
  }
  __syncthreads();
  for (int g=1; g<G; ++g){
    float cx=cent[0], cy=cent[1], cz=cent[2];
    float bv=-1.f; int bi=0;
    #pragma unroll
    for (int i=0;i<PPT;++i){
      float dx=__fsub_rn(px[i],cx), dy=__fsub_rn(py[i],cy), dz=__fsub_rn(pz[i],cz);
      float d = __fadd_rn(__fadd_rn(__fmul_rn(dx,dx),__fmul_rn(dy,dy)),__fmul_rn(dz,dz));
      float nd = fminf(dist[i], d);
      dist[i]=nd;
      int gi = t + i*512;
      if (nd > bv || (nd==bv && gi<bi)) { bv=nd; bi=gi; }
    }
    #pragma unroll
    for (int off=32; off>0; off>>=1){
      float ov = __shfl_down(bv, off);
      int   oi = __shfl_down(bi, off);
      if (ov > bv || (ov==bv && oi<bi)){ bv=ov; bi=oi; }
    }
    if ((t&63)==0){ redv[t>>6]=bv; redi[t>>6]=bi; }
    __syncthreads();
    if (t==0){
      float Bv=redv[0]; int Bi=redi[0];
      #pragma unroll
      for (int wv=1; wv<8; ++wv){
        if (redv[wv] > Bv || (redv[wv]==Bv && redi[wv]<Bi)){ Bv=redv[wv]; Bi=redi[wv]; }
      }
      oidx[(size_t)b*G + g] = Bi;
      float sx=xl[Bi*3], sy=xl[Bi*3+1], sz=xl[Bi*3+2];
      float* op = oxyz + ((size_t)b*G + g)*3;
      op[0]=sx; op[1]=sy; op[2]=sz;
      cent[0]=sx; cent[1]=sy; cent[2]=sz;
    }
    __syncthreads();
  }
}

// ---------------------------------------------------------------------------
// EdgeConv pre-norm: y[o,k] = sum_c w[o,c] * e[c,k], e = [nbr-xq ; xq].
// Emits per-(q,o) max/min over k (monotone-GN trick: GN affine is per-channel
// monotone, so max over K commutes -> keep max and min, pick in finalize) and
// per-(b,group) sum/sumsq (group == wave, since 256 threads / 4 groups = 64).
template<int CF, int COUT>
__global__ __launch_bounds__(256) void edge_kernel(
    const float* __restrict__ fk, const int* __restrict__ sel,
    const int* __restrict__ knn, const float* __restrict__ w,
    float* __restrict__ mm, float* __restrict__ stats, int Nq, int Nk){
  constexpr int CIN = 2*CF;
  constexpr int P   = 256/COUT;   // threads per output channel
  constexpr int KP  = 16/P;       // k's per thread
  constexpr int WL  = COUT+1;     // pad -> odd stride, no bank conflicts
  __shared__ float wt[CIN*WL];
  __shared__ __align__(16) float e[CIN*20];   // stride 20: float4-aligned rows
  __shared__ float fqs[CF];
  __shared__ int   nid[16];
  __shared__ float smx[256], smn[256];
  int b = blockIdx.y, q = blockIdx.x, t = threadIdx.x;
  if (t<16) nid[t] = knn[((size_t)b*Nq+q)*16+t];
  if (t<CF){
    int qi = sel ? sel[b*Nq+q] : q;
    fqs[t] = fk[((size_t)b*Nk+qi)*CF+t];
  }
  for (int i=t;i<COUT*CIN;i+=256){
    int o = i/CIN, c = i - o*CIN;
    wt[c*WL+o] = w[i];
  }
  __syncthreads();
  for (int i=t;i<CF*16;i+=256){
    int k = i/CF, c = i - k*CF;
    float v  = fk[((size_t)b*Nk + nid[k])*CF + c];
    float fq = fqs[c];
    e[c*20+k]      = v - fq;
    e[(CF+c)*20+k] = fq;
  }
  __syncthreads();
  int o = t/P, h = t - o*P;
  float y[KP];
  #pragma unroll
  for (int j=0;j<KP;++j) y[j]=0.f;
  for (int c=0;c<CIN;++c){
    float wa = wt[c*WL+o];
    const float* ep = &e[c*20 + h*KP];
    if constexpr (KP==2){
      float2 ev = *(const float2*)ep;
      y[0]=fmaf(wa, ev.x, y[0]); y[1]=fmaf(wa, ev.y, y[1]);
    } else {
      #pragma unroll
      for (int j0=0;j0<KP;j0+=4){
        float4 ev = *(const float4*)(ep+j0);
        y[j0+0]=fmaf(wa,ev.x,y[j0+0]); y[j0+1]=fmaf(wa,ev.y,y[j0+1]);
        y[j0+2]=fmaf(wa,ev.z,y[j0+2]); y[j0+3]=fmaf(wa,ev.w,y[j0+3]);
      }
    }
  }
  float lmx=-3.4e38f, lmn=3.4e38f, ls=0.f, ls2=0.f;
  #pragma unroll
  for (int j=0;j<KP;++j){
    float v=y[j];
    lmx=fmaxf(lmx,v); lmn=fminf(lmn,v);
    ls += v; ls2 = fmaf(v,v,ls2);
  }
  #pragma unroll
  for (int off=32; off>0; off>>=1){
    ls  += __shfl_down(ls, off);
    ls2 += __shfl_down(ls2, off);
  }
  if ((t&63)==0){   // wave w covers exactly group w
    float* sp = stats + ((size_t)b*4 + (t>>6))*2;
    atomicAdd(sp, ls); atomicAdd(sp+1, ls2);
  }
  smx[t]=lmx; smn[t]=lmn;
  __syncthreads();
  if (h==0){
    float mx=smx[t], mn=smn[t];
    #pragma unroll
    for (int j=1;j<P;++j){ mx=fmaxf(mx,smx[t+j]); mn=fminf(mn,smn[t+j]); }
    float* mp = mm + (((size_t)b*Nq+q)*COUT + o)*2;
    mp[0]=mx; mp[1]=mn;
  }
}

// ---------------------------------------------------------------------------
// finalize: GN affine on the max (or min if a<0) + LeakyReLU. fp32 internal out,
// or transposed final output (bf16 or fp32 per flag) into d_out.
__global__ __launch_bounds__(256) void fin_kernel(
    const float* __restrict__ mm, const float* __restrict__ stats,
    const float* __restrict__ gam, const float* __restrict__ bet,
    float* __restrict__ fo, void* __restrict__ outbase, const int* __restrict__ flag,
    int outoff, int Nq, int COUT, float invcnt, int total){
  int i = blockIdx.x*256 + threadIdx.x;
  if (i>=total) return;
  int o = i % COUT;
  int r = i / COUT;
  int q = r % Nq;
  int b = r / Nq;
  int g = o / (COUT>>2);
  const float* sp = stats + ((size_t)b*4+g)*2;
  float mean = sp[0]*invcnt;
  float var  = fmaxf(sp[1]*invcnt - mean*mean, 0.f);
  float inv  = 1.0f / sqrtf(var + 1e-5f);
  float a  = gam[o] * inv;
  float bb = bet[o] - a*mean;
  const float* mp = mm + (size_t)i*2;
  float xv = (a>=0.f) ? mp[0] : mp[1];  // monotone affine: max commutes (min if a<0)
  float v = fmaf(a, xv, bb);
  v = (v>=0.f) ? v : 0.2f*v;
  if (fo) fo[i]=v;
  if (outbase){
    int idx = outoff + ((b*COUT + o)*Nq + q);
    if (*flag) ((float*)outbase)[idx] = v;
    else       ((unsigned short*)outbase)[idx] = f2bf(v);
  }
}

__global__ __launch_bounds__(256) void coor_kernel(
    const float* __restrict__ xyz2, void* __restrict__ outbase,
    const int* __restrict__ flag){
  int i = blockIdx.x*256+threadIdx.x;   // 32*3*128
  int m = i & 127;
  int c = (i>>7) % 3;
  int b = i / 384;
  float v = xyz2[((size_t)b*128+m)*3 + c];
  if (*flag) ((float*)outbase)[i] = v;
  else       ((unsigned short*)outbase)[i] = f2bf(v);
}

// ---------------------------------------------------------------------------
extern "C" void kernel_launch(void* const* d_in, const int* in_sizes, int n_in,
                              void* d_out, int out_size, void* d_ws, size_t ws_size,
                              hipStream_t stream){
  float* W    = (float*)d_ws;
  float* xyz0 = W;                      // 196608
  float* f0   = W + 196608;             // 524288
  float* f1   = W + 720896;             // 2097152
  float* xyz1 = W + 2818048;            // 49152
  float* f2   = W + 2867200;            // 1048576
  float* f3   = W + 3915776;            // 1048576
  float* xyz2 = W + 4964352;            // 12288
  float* stats= W + 4976640;            // 1024 (4 layers x 32 x 4 x 2)
  int*   flag = (int*)(W + 4977664);    // 16 (pad)
  float* PRM  = W + 4977680;            // 29792 canonical fp32 params
  int*  idx1  = (int*)(W + 5007472);    // 16384
  int*  idx2  = (int*)(W + 5023856);    // 4096
  float* SCR  = W + 5027952;            // aliased per-layer scratch
  int*   knnb = (int*)SCR;              // <= 1048576 ints
  float* mmb  = SCR + 1048576;          // <= 4194304 floats
  // total ~ 40.9 MB

  // canonical param layout
  float* cw_in = PRM;          // 24
  float* cb_in = PRM+24;       // 8
  float* cw1 = PRM+32;   float* cg1 = PRM+544;   float* cbb1 = PRM+576;   // 512,32,32
  float* cw2 = PRM+608;  float* cg2 = PRM+4704;  float* cbb2 = PRM+4768;  // 4096,64,64
  float* cw3 = PRM+4832; float* cg3 = PRM+13024; float* cbb3 = PRM+13088; // 8192,64,64
  float* cw4 = PRM+13152;float* cg4 = PRM+29536; float* cbb4 = PRM+29664; // 16384,128,128

  detect_kernel<<<1,256,0,stream>>>((const unsigned short*)d_in[0], flag);

  PConv pc;
  const int psz[14] = {24,8,512,32,32,4096,64,64,8192,64,64,16384,128,128};
  float* pdst[14] = {cw_in,cb_in,cw1,cg1,cbb1,cw2,cg2,cbb2,cw3,cg3,cbb3,cw4,cg4,cbb4};
  for (int j=0;j<14;++j){ pc.s[j]=d_in[j+1]; pc.d[j]=pdst[j]; pc.sz[j]=psz[j]; }
  conv_params_kernel<<<117,256,0,stream>>>(pc, flag);

  prep_kernel<<<256,256,0,stream>>>(d_in[0], flag, cw_in, cb_in, xyz0, f0, stats);

  // ---- layer 1: 2048q/2048k, 16 -> 32
  knn_kernel<2048><<<dim3(8,32),256,0,stream>>>(xyz0, xyz0, 2048, knnb);
  edge_kernel<8,32><<<dim3(2048,32),256,0,stream>>>(f0, nullptr, knnb, cw1, mmb, stats+0, 2048, 2048);
  fin_kernel<<<8192,256,0,stream>>>(mmb, stats+0, cg1, cbb1, f1, nullptr, flag, 0, 2048, 32, 1.f/262144.f, 2097152);

  // ---- FPS 2048 -> 512
  fps_kernel<2048,512><<<32,512,0,stream>>>(xyz0, idx1, xyz1);

  // ---- layer 2: 512q/2048k, 64 -> 64 (queries gathered via idx1)
  knn_kernel<2048><<<dim3(2,32),256,0,stream>>>(xyz1, xyz0, 512, knnb);
  edge_kernel<32,64><<<dim3(512,32),256,0,stream>>>(f1, idx1, knnb, cw2, mmb, stats+256, 512, 2048);
  fin_kernel<<<4096,256,0,stream>>>(mmb, stats+256, cg2, cbb2, f2, nullptr, flag, 0, 512, 64, 1.f/131072.f, 1048576);

  // ---- layer 3: 512q/512k, 128 -> 64
  knn_kernel<512><<<dim3(2,32),256,0,stream>>>(xyz1, xyz1, 512, knnb);
  edge_kernel<64,64><<<dim3(512,32),256,0,stream>>>(f2, nullptr, knnb, cw3, mmb, stats+512, 512, 512);
  fin_kernel<<<4096,256,0,stream>>>(mmb, stats+512, cg3, cbb3, f3, nullptr, flag, 0, 512, 64, 1.f/131072.f, 1048576);

  // ---- FPS 512 -> 128
  fps_kernel<512,128><<<32,512,0,stream>>>(xyz1, idx2, xyz2);

  // ---- layer 4: 128q/512k, 128 -> 128 (queries via idx2) -> final f output
  knn_kernel<512><<<dim3(1,32),256,0,stream>>>(xyz2, xyz1, 128, knnb);
  edge_kernel<64,128><<<dim3(128,32),256,0,stream>>>(f3, idx2, knnb, cw4, mmb, stats+768, 128, 512);
  fin_kernel<<<2048,256,0,stream>>>(mmb, stats+768, cg4, cbb4, nullptr, d_out, flag, 12288, 128, 128, 1.f/65536.f, 524288);

  // ---- coor output (B,3,128)
  coor_kernel<<<48,256,0,stream>>>(xyz2, d_out, flag);
}

// Round 3
// 3377.755 us; speedup vs baseline: 1.8714x; 1.8714x over previous
//
#include <hip/hip_runtime.h>
#include <hip/hip_bf16.h>

#define DEV __device__ __forceinline__

DEV float bf2f(unsigned short u){ return __uint_as_float(((unsigned)u)<<16); }
DEV unsigned short f2bf(float f){
  unsigned u = __float_as_uint(f);
  u += 0x7fffu + ((u>>16)&1u);   // RNE
  return (unsigned short)(u>>16);
}

// ---------------------------------------------------------------------------
// dtype detection: genuine bf16 N(0,1) data never has exponent >= 0xC0;
// fp32 read as ushorts has ~25% such halfwords. flag=1 -> inputs fp32.
__global__ __launch_bounds__(256) void detect_kernel(
    const unsigned short* __restrict__ x, int* __restrict__ flag){
  __shared__ int cnt;
  if (threadIdx.x==0) cnt = 0;
  __syncthreads();
  int local = 0;
  for (int i=threadIdx.x; i<4096; i+=256){
    int e = (x[i]>>7)&0xFF;
    if (e >= 0xC0) local++;
  }
  atomicAdd(&cnt, local);
  __syncthreads();
  if (threadIdx.x==0) *flag = (cnt > 64) ? 1 : 0;
}

// ---------------------------------------------------------------------------
struct PConv {
  const void* s[14];
  float*      d[14];
  int         sz[14];
};
__global__ __launch_bounds__(256) void conv_params_kernel(PConv p, const int* __restrict__ flag){
  bool isf = (*flag != 0);
  int i = blockIdx.x*256 + threadIdx.x;
  int seg = 0, off = i;
  #pragma unroll
  for (seg=0; seg<14; ++seg){
    if (off < p.sz[seg]) break;
    off -= p.sz[seg];
  }
  if (seg >= 14) return;
  float v = isf ? ((const float*)p.s[seg])[off]
                : bf2f(((const unsigned short*)p.s[seg])[off]);
  p.d[seg][off] = v;
}

// ---------------------------------------------------------------------------
// prep: coords (B,3,2048)->(B,2048,3) fp32, f0 = w_in@x + b_in, zero stats(8192).
__global__ __launch_bounds__(256) void prep_kernel(
    const void* __restrict__ xraw, const int* __restrict__ flag,
    const float* __restrict__ w_in, const float* __restrict__ b_in,
    float* __restrict__ xyz0, float* __restrict__ f0, float* __restrict__ stats){
  int i = blockIdx.x*256 + threadIdx.x;          // 32*2048 threads
  if (i < 8192) stats[i] = 0.f;
  bool isf = (*flag != 0);
  int b = i >> 11, n = i & 2047;
  size_t base = (size_t)b*3*2048 + n;
  float X, Y, Z;
  if (isf){
    const float* xf = (const float*)xraw;
    X = xf[base]; Y = xf[base+2048]; Z = xf[base+4096];
  } else {
    const unsigned short* xu = (const unsigned short*)xraw;
    X = bf2f(xu[base]); Y = bf2f(xu[base+2048]); Z = bf2f(xu[base+4096]);
  }
  float* o3 = xyz0 + (size_t)i*3;
  o3[0]=X; o3[1]=Y; o3[2]=Z;
  float* fo = f0 + (size_t)i*8;
  #pragma unroll
  for (int o=0;o<8;++o){
    fo[o] = w_in[o*3+0]*X + w_in[o*3+1]*Y + w_in[o*3+2]*Z + b_in[o];
  }
}

// ---------------------------------------------------------------------------
// kNN: 16 smallest (ties -> lower index), exact fp32 no-FMA replication of ref.
// float4 LDS (x,y,z,sq) + 8-wide unroll for ILP; min-gate skips insert scan.
template<int NK>
__global__ void knn_kernel(
    const float* __restrict__ qxyz, const float* __restrict__ kxyz,
    int Nq, int* __restrict__ oidx){
  __shared__ __align__(16) float4 kd[NK];
  int b = blockIdx.y, t = threadIdx.x, BS = blockDim.x;
  for (int i=t; i<NK; i+=BS){
    const float* p = kxyz + ((size_t)b*NK + i)*3;
    float X=p[0], Y=p[1], Z=p[2];
    float sk = __fadd_rn(__fadd_rn(__fmul_rn(X,X),__fmul_rn(Y,Y)),__fmul_rn(Z,Z));
    kd[i] = make_float4(X,Y,Z,sk);
  }
  __syncthreads();
  int q = blockIdx.x*BS + t;
  if (q >= Nq) return;
  const float* qp = qxyz + ((size_t)b*Nq + q)*3;
  float QX=qp[0], QY=qp[1], QZ=qp[2];
  float sq = __fadd_rn(__fadd_rn(__fmul_rn(QX,QX),__fmul_rn(QY,QY)),__fmul_rn(QZ,QZ));
  float dl[16]; int il[16];
  #pragma unroll
  for (int j=0;j<16;++j){ dl[j]=3.4e38f; il[j]=-1; }
  for (int m=0; m<NK; m+=8){
    float d[8];
    #pragma unroll
    for (int j=0;j<8;++j){
      float4 c = kd[m+j];
      float dot = __fadd_rn(__fadd_rn(__fmul_rn(QX,c.x),__fmul_rn(QY,c.y)),__fmul_rn(QZ,c.z));
      d[j] = __fsub_rn(__fadd_rn(sq, c.w), __fmul_rn(2.0f,dot));
    }
    float dmin = fminf(fminf(fminf(d[0],d[1]),fminf(d[2],d[3])),
                       fminf(fminf(d[4],d[5]),fminf(d[6],d[7])));
    if (dmin < dl[15]){
      #pragma unroll
      for (int j=0;j<8;++j){
        float dj = d[j];
        if (dj < dl[15]){               // strict <: equal dist keeps earlier index
          dl[15]=dj; il[15]=m+j;
          #pragma unroll
          for (int s=15;s>0;--s){
            if (dl[s] < dl[s-1]){       // strict <: stable among equals
              float td=dl[s]; dl[s]=dl[s-1]; dl[s-1]=td;
              int   ti=il[s]; il[s]=il[s-1]; il[s-1]=ti;
            }
          }
        }
      }
    }
  }
  int* op = oidx + ((size_t)b*Nq + q)*16;
  #pragma unroll
  for (int j=0;j<16;++j) op[j]=il[j];
}

// ---------------------------------------------------------------------------
// FPS: exact fp32 no-FMA; one barrier per step (double-buffered wave slots),
// winner index carried in registers by every thread.
template<int NP,int G,int T>
__global__ __launch_bounds__(T) void fps_kernel(
    const float* __restrict__ xyz, int* __restrict__ oidx, float* __restrict__ oxyz){
  constexpr int PPT = NP/T, W = T/64;
  __shared__ float xl[NP*3];
  __shared__ float redv[2][W];
  __shared__ int   redi[2][W];
  int b = blockIdx.x, t = threadIdx.x;
  for (int i=t;i<NP;i+=T){
    const float* p = xyz + ((size_t)b*NP + i)*3;
    xl[i*3+0]=p[0]; xl[i*3+1]=p[1]; xl[i*3+2]=p[2];
  }
  __syncthreads();
  float px[PPT], py[PPT], pz[PPT], dist[PPT];
  #pragma unroll
  for (int i=0;i<PPT;++i){
    int gi = t + i*T;
    px[i]=xl[gi*3]; py[i]=xl[gi*3+1]; pz[i]=xl[gi*3+2];
    dist[i]=1e10f;
  }
  int Bi = 0;
  if (t==0){
    oidx[(size_t)b*G] = 0;
    oxyz[(size_t)b*G*3+0]=xl[0]; oxyz[(size_t)b*G*3+1]=xl[1]; oxyz[(size_t)b*G*3+2]=xl[2];
  }
  for (int g=1; g<G; ++g){
    float cx=xl[3*Bi], cy=xl[3*Bi+1], cz=xl[3*Bi+2];
    float bv=-1.f; int bix=0;
    #pragma unroll
    for (int i=0;i<PPT;++i){
      float dx=__fsub_rn(px[i],cx), dy=__fsub_rn(py[i],cy), dz=__fsub_rn(pz[i],cz);
      float d = __fadd_rn(__fadd_rn(__fmul_rn(dx,dx),__fmul_rn(dy,dy)),__fmul_rn(dz,dz));
      float nd = fminf(dist[i], d);
      dist[i]=nd;
      int gi = t + i*T;
      if (nd > bv || (nd==bv && gi<bix)) { bv=nd; bix=gi; }
    }
    #pragma unroll
    for (int off=32; off>0; off>>=1){
      float ov = __shfl_down(bv, off);
      int   oi = __shfl_down(bix, off);
      if (ov > bv || (ov==bv && oi<bix)){ bv=ov; bix=oi; }
    }
    int par = g & 1;
    if ((t&63)==0){ redv[par][t>>6]=bv; redi[par][t>>6]=bix; }
    __syncthreads();
    float Bv = redv[par][0]; Bi = redi[par][0];
    #pragma unroll
    for (int wv=1; wv<W; ++wv){
      float rv = redv[par][wv]; int ri = redi[par][wv];
      if (rv > Bv || (rv==Bv && ri<Bi)){ Bv=rv; Bi=ri; }
    }
    if (t==0){
      oidx[(size_t)b*G + g] = Bi;
      float* op = oxyz + ((size_t)b*G + g)*3;
      op[0]=xl[3*Bi]; op[1]=xl[3*Bi+1]; op[2]=xl[3*Bi+2];
    }
  }
}

// ---------------------------------------------------------------------------
// EdgeConv pre-norm, query-batched. Block: QB queries, 256 threads, thread owns
// (ql, o, o+COUT/2) and ALL 16 k's. Key identity: the xq half of the edge
// feature is k-invariant, so y[o,k] = sum_{c<CF} w1[o,c]*nbr[c,k] + z[o],
// z = sum_c (w2[o,c]-w1[o,c])*fq[c]. Weights staged per CF-half (LDS <= 52KB).
// Stats: thread -> LDS atomic (8 floats) -> 8-way bucketed global atomics.
template<int CF,int COUT,int QB>
__global__ __launch_bounds__(256) void edge_kernel(
    const float* __restrict__ fk, const int* __restrict__ sel,
    const int* __restrict__ knn, const float* __restrict__ w,
    float* __restrict__ mm, float* __restrict__ stats, int Nq, int Nk){
  constexpr int CIN = 2*CF;
  constexpr int GPQ = COUT/2;        // threads per query (2 outputs/thread)
  constexpr int WS  = COUT+1;        // padded weight stride (conflict-free stage)
  constexpr int ESTR= CF*16+8;       // per-query e stride (+8 staggers banks)
  static_assert(QB*GPQ == 256, "block mapping");
  __shared__ float wtb[CF*WS];
  __shared__ __align__(16) float e[QB*ESTR];
  __shared__ float fqs[QB*CF];
  __shared__ float sS[8];            // [0..3]=sum per group, [4..7]=sumsq
  int b = blockIdx.y, t = threadIdx.x;
  int q0 = blockIdx.x*QB;

  if (t<8) sS[t]=0.f;
  // stage fq rows (query features)
  for (int i=t; i<QB*CF; i+=256){
    int ql = i/CF, c = i&(CF-1);
    int qi = sel ? sel[b*Nq + q0 + ql] : (q0 + ql);
    fqs[i] = fk[((size_t)b*Nk + qi)*CF + c];
  }
  // stage weight half A (c < CF)
  for (int i=t; i<CF*COUT; i+=256){
    int o = i/CF, c = i&(CF-1);
    wtb[c*WS+o] = w[o*CIN + c];
  }
  // gather raw neighbor rows into e[ql][c][k]
  if (t < QB*16){
    int ql = t>>4, k = t&15;
    int nid = knn[((size_t)b*Nq + q0 + ql)*16 + k];
    const float4* row = (const float4*)(fk + ((size_t)b*Nk + nid)*CF);
    float* ep = e + ql*ESTR + k;
    #pragma unroll
    for (int c4=0; c4<CF/4; ++c4){
      float4 v = row[c4];
      ep[(c4*4+0)*16]=v.x; ep[(c4*4+1)*16]=v.y; ep[(c4*4+2)*16]=v.z; ep[(c4*4+3)*16]=v.w;
    }
  }
  __syncthreads();

  int ql = t/GPQ, o = t%GPQ;
  const float* eb = e + ql*ESTR;
  const float* fqb = fqs + ql*CF;
  float y0[16], y1[16];
  #pragma unroll
  for (int k=0;k<16;++k){ y0[k]=0.f; y1[k]=0.f; }
  float zA0=0.f, zA1=0.f;
  for (int c=0;c<CF;++c){
    float w0 = wtb[c*WS+o];
    float w1 = wtb[c*WS+o+GPQ];
    float fqc = fqb[c];
    zA0 = fmaf(w0,fqc,zA0); zA1 = fmaf(w1,fqc,zA1);
    const float4* ev4 = (const float4*)(eb + c*16);
    #pragma unroll
    for (int k4=0;k4<4;++k4){
      float4 ev = ev4[k4];
      y0[k4*4+0]=fmaf(w0,ev.x,y0[k4*4+0]); y0[k4*4+1]=fmaf(w0,ev.y,y0[k4*4+1]);
      y0[k4*4+2]=fmaf(w0,ev.z,y0[k4*4+2]); y0[k4*4+3]=fmaf(w0,ev.w,y0[k4*4+3]);
      y1[k4*4+0]=fmaf(w1,ev.x,y1[k4*4+0]); y1[k4*4+1]=fmaf(w1,ev.y,y1[k4*4+1]);
      y1[k4*4+2]=fmaf(w1,ev.z,y1[k4*4+2]); y1[k4*4+3]=fmaf(w1,ev.w,y1[k4*4+3]);
    }
  }
  __syncthreads();
  // stage weight half B (c >= CF)
  for (int i=t; i<CF*COUT; i+=256){
    int oo = i/CF, c = i&(CF-1);
    wtb[c*WS+oo] = w[oo*CIN + CF + c];
  }
  __syncthreads();
  float zB0=0.f, zB1=0.f;
  for (int c=0;c<CF;++c){
    float fqc = fqb[c];
    zB0 = fmaf(wtb[c*WS+o],fqc,zB0);
    zB1 = fmaf(wtb[c*WS+o+GPQ],fqc,zB1);
  }
  float z0 = zB0 - zA0, z1 = zB1 - zA1;

  float mx0=-3.4e38f, mn0=3.4e38f, s0=0.f, q0s=0.f;
  float mx1=-3.4e38f, mn1=3.4e38f, s1=0.f, q1s=0.f;
  #pragma unroll
  for (int k=0;k<16;++k){
    float v0 = y0[k]+z0, v1 = y1[k]+z1;
    mx0=fmaxf(mx0,v0); mn0=fminf(mn0,v0); s0+=v0; q0s=fmaf(v0,v0,q0s);
    mx1=fmaxf(mx1,v1); mn1=fminf(mn1,v1); s1+=v1; q1s=fmaf(v1,v1,q1s);
  }
  int g0 = o/(COUT/4);               // in {0,1}; second output is g0+2
  atomicAdd(&sS[g0],   s0); atomicAdd(&sS[4+g0],   q0s);
  atomicAdd(&sS[g0+2], s1); atomicAdd(&sS[6+g0],   q1s);
  size_t mi0 = ((size_t)b*Nq + q0 + ql)*COUT + o;
  ((float2*)mm)[mi0]       = make_float2(mx0,mn0);
  ((float2*)mm)[mi0+GPQ]   = make_float2(mx1,mn1);
  __syncthreads();
  if (t<8){
    int g = t>>1, which = t&1;
    float val = which ? sS[4+g] : sS[g];
    atomicAdd(&stats[(((size_t)b*4+g)*8 + (blockIdx.x&7))*2 + which], val);
  }
}

// ---------------------------------------------------------------------------
// finalize: sum stat buckets, GN affine on max (min if a<0) + LeakyReLU.
__global__ __launch_bounds__(256) void fin_kernel(
    const float* __restrict__ mm, const float* __restrict__ stats,
    const float* __restrict__ gam, const float* __restrict__ bet,
    float* __restrict__ fo, void* __restrict__ outbase, const int* __restrict__ flag,
    int outoff, int Nq, int COUT, float invcnt, int total){
  for (int i = blockIdx.x*256 + threadIdx.x; i<total; i += gridDim.x*256){
    int o = i % COUT;
    int r = i / COUT;
    int q = r % Nq;
    int b = r / Nq;
    int g = o / (COUT>>2);
    const float* sp = stats + ((size_t)(b*4+g))*16;
    float s=0.f, s2=0.f;
    #pragma unroll
    for (int nb=0;nb<8;++nb){ s += sp[nb*2]; s2 += sp[nb*2+1]; }
    float mean = s*invcnt;
    float var  = fmaxf(s2*invcnt - mean*mean, 0.f);
    float inv  = 1.0f / sqrtf(var + 1e-5f);
    float a  = gam[o] * inv;
    float bb = bet[o] - a*mean;
    const float* mp = mm + (size_t)i*2;
    float xv = (a>=0.f) ? mp[0] : mp[1];  // monotone affine: max commutes
    float v = fmaf(a, xv, bb);
    v = (v>=0.f) ? v : 0.2f*v;
    if (fo) fo[i]=v;
    if (outbase){
      int idx = outoff + ((b*COUT + o)*Nq + q);
      if (*flag) ((float*)outbase)[idx] = v;
      else       ((unsigned short*)outbase)[idx] = f2bf(v);
    }
  }
}

__global__ __launch_bounds__(256) void coor_kernel(
    const float* __restrict__ xyz2, void* __restrict__ outbase,
    const int* __restrict__ flag){
  int i = blockIdx.x*256+threadIdx.x;   // 32*3*128
  int m = i & 127;
  int c = (i>>7) % 3;
  int b = i / 384;
  float v = xyz2[((size_t)b*128+m)*3 + c];
  if (*flag) ((float*)outbase)[i] = v;
  else       ((unsigned short*)outbase)[i] = f2bf(v);
}

// ---------------------------------------------------------------------------
extern "C" void kernel_launch(void* const* d_in, const int* in_sizes, int n_in,
                              void* d_out, int out_size, void* d_ws, size_t ws_size,
                              hipStream_t stream){
  float* W    = (float*)d_ws;
  float* xyz0 = W;                      // 196608
  float* f0   = W + 196608;             // 524288
  float* f1   = W + 720896;             // 2097152
  float* xyz1 = W + 2818048;            // 49152
  float* f2   = W + 2867200;            // 1048576
  float* f3   = W + 3915776;            // 1048576
  float* xyz2 = W + 4964352;            // 12288
  float* stats= W + 4976640;            // 8192 (4 layers x 32 x 4 x 8buckets x 2)
  int*   flag = (int*)(W + 4984832);    // 16 (pad)
  float* PRM  = W + 4984848;            // 29792 canonical fp32 params
  int*  idx1  = (int*)(W + 5014640);    // 16384
  int*  idx2  = (int*)(W + 5031024);    // 4096
  float* SCR  = W + 5035120;            // aliased per-layer scratch
  int*   knnb = (int*)SCR;              // <= 1048576 ints
  float* mmb  = SCR + 1048576;          // <= 4194304 floats
  // total ~ 41.1 MB

  float* cw_in = PRM;          // 24
  float* cb_in = PRM+24;       // 8
  float* cw1 = PRM+32;   float* cg1 = PRM+544;   float* cbb1 = PRM+576;   // 512,32,32
  float* cw2 = PRM+608;  float* cg2 = PRM+4704;  float* cbb2 = PRM+4768;  // 4096,64,64
  float* cw3 = PRM+4832; float* cg3 = PRM+13024; float* cbb3 = PRM+13088; // 8192,64,64
  float* cw4 = PRM+13152;float* cg4 = PRM+29536; float* cbb4 = PRM+29664; // 16384,128,128

  detect_kernel<<<1,256,0,stream>>>((const unsigned short*)d_in[0], flag);

  PConv pc;
  const int psz[14] = {24,8,512,32,32,4096,64,64,8192,64,64,16384,128,128};
  float* pdst[14] = {cw_in,cb_in,cw1,cg1,cbb1,cw2,cg2,cbb2,cw3,cg3,cbb3,cw4,cg4,cbb4};
  for (int j=0;j<14;++j){ pc.s[j]=d_in[j+1]; pc.d[j]=pdst[j]; pc.sz[j]=psz[j]; }
  conv_params_kernel<<<117,256,0,stream>>>(pc, flag);

  prep_kernel<<<256,256,0,stream>>>(d_in[0], flag, cw_in, cb_in, xyz0, f0, stats);

  // ---- layer 1: 2048q/2048k, 16 -> 32
  knn_kernel<2048><<<dim3(8,32),256,0,stream>>>(xyz0, xyz0, 2048, knnb);
  edge_kernel<8,32,16><<<dim3(128,32),256,0,stream>>>(f0, nullptr, knnb, cw1, mmb, stats+0, 2048, 2048);
  fin_kernel<<<1024,256,0,stream>>>(mmb, stats+0, cg1, cbb1, f1, nullptr, flag, 0, 2048, 32, 1.f/262144.f, 2097152);

  // ---- FPS 2048 -> 512
  fps_kernel<2048,512,512><<<32,512,0,stream>>>(xyz0, idx1, xyz1);

  // ---- layer 2: 512q/2048k, 64 -> 64 (queries gathered via idx1)
  knn_kernel<2048><<<dim3(2,32),256,0,stream>>>(xyz1, xyz0, 512, knnb);
  edge_kernel<32,64,8><<<dim3(64,32),256,0,stream>>>(f1, idx1, knnb, cw2, mmb, stats+2048, 512, 2048);
  fin_kernel<<<1024,256,0,stream>>>(mmb, stats+2048, cg2, cbb2, f2, nullptr, flag, 0, 512, 64, 1.f/131072.f, 1048576);

  // ---- layer 3: 512q/512k, 128 -> 64
  knn_kernel<512><<<dim3(2,32),256,0,stream>>>(xyz1, xyz1, 512, knnb);
  edge_kernel<64,64,8><<<dim3(64,32),256,0,stream>>>(f2, nullptr, knnb, cw3, mmb, stats+4096, 512, 512);
  fin_kernel<<<1024,256,0,stream>>>(mmb, stats+4096, cg3, cbb3, f3, nullptr, flag, 0, 512, 64, 1.f/131072.f, 1048576);

  // ---- FPS 512 -> 128
  fps_kernel<512,128,512><<<32,512,0,stream>>>(xyz1, idx2, xyz2);

  // ---- layer 4: 128q/512k, 128 -> 128 (queries via idx2) -> final f output
  knn_kernel<512><<<dim3(1,32),128,0,stream>>>(xyz2, xyz1, 128, knnb);
  edge_kernel<64,128,4><<<dim3(32,32),256,0,stream>>>(f3, idx2, knnb, cw4, mmb, stats+6144, 128, 512);
  fin_kernel<<<1024,256,0,stream>>>(mmb, stats+6144, cg4, cbb4, nullptr, d_out, flag, 12288, 128, 128, 1.f/65536.f, 524288);

  // ---- coor output (B,3,128)
  coor_kernel<<<48,256,0,stream>>>(xyz2, d_out, flag);
}

// Round 4
// 2643.535 us; speedup vs baseline: 2.3911x; 1.2777x over previous
//
#include <hip/hip_runtime.h>
#include <hip/hip_bf16.h>

#define DEV __device__ __forceinline__

DEV float bf2f(unsigned short u){ return __uint_as_float(((unsigned)u)<<16); }
DEV unsigned short f2bf(float f){
  unsigned u = __float_as_uint(f);
  u += 0x7fffu + ((u>>16)&1u);   // RNE
  return (unsigned short)(u>>16);
}

// ---------------------------------------------------------------------------
// dtype detection: genuine bf16 N(0,1) data never has exponent >= 0xC0;
// fp32 read as ushorts has ~25% such halfwords. flag=1 -> inputs fp32.
__global__ __launch_bounds__(256) void detect_kernel(
    const unsigned short* __restrict__ x, int* __restrict__ flag){
  __shared__ int cnt;
  if (threadIdx.x==0) cnt = 0;
  __syncthreads();
  int local = 0;
  for (int i=threadIdx.x; i<4096; i+=256){
    int e = (x[i]>>7)&0xFF;
    if (e >= 0xC0) local++;
  }
  atomicAdd(&cnt, local);
  __syncthreads();
  if (threadIdx.x==0) *flag = (cnt > 64) ? 1 : 0;
}

// ---------------------------------------------------------------------------
struct PConv {
  const void* s[14];
  float*      d[14];
  int         sz[14];
};
__global__ __launch_bounds__(256) void conv_params_kernel(PConv p, const int* __restrict__ flag){
  bool isf = (*flag != 0);
  int i = blockIdx.x*256 + threadIdx.x;
  int seg = 0, off = i;
  #pragma unroll
  for (seg=0; seg<14; ++seg){
    if (off < p.sz[seg]) break;
    off -= p.sz[seg];
  }
  if (seg >= 14) return;
  float v = isf ? ((const float*)p.s[seg])[off]
                : bf2f(((const unsigned short*)p.s[seg])[off]);
  p.d[seg][off] = v;
}

// ---------------------------------------------------------------------------
// prep: coords (B,3,2048)->(B,2048,3) fp32, f0 = w_in@x + b_in, zero stats(8192).
__global__ __launch_bounds__(256) void prep_kernel(
    const void* __restrict__ xraw, const int* __restrict__ flag,
    const float* __restrict__ w_in, const float* __restrict__ b_in,
    float* __restrict__ xyz0, float* __restrict__ f0, float* __restrict__ stats){
  int i = blockIdx.x*256 + threadIdx.x;          // 32*2048 threads
  if (i < 8192) stats[i] = 0.f;
  bool isf = (*flag != 0);
  int b = i >> 11, n = i & 2047;
  size_t base = (size_t)b*3*2048 + n;
  float X, Y, Z;
  if (isf){
    const float* xf = (const float*)xraw;
    X = xf[base]; Y = xf[base+2048]; Z = xf[base+4096];
  } else {
    const unsigned short* xu = (const unsigned short*)xraw;
    X = bf2f(xu[base]); Y = bf2f(xu[base+2048]); Z = bf2f(xu[base+4096]);
  }
  float* o3 = xyz0 + (size_t)i*3;
  o3[0]=X; o3[1]=Y; o3[2]=Z;
  float* fo = f0 + (size_t)i*8;
  #pragma unroll
  for (int o=0;o<8;++o){
    fo[o] = w_in[o*3+0]*X + w_in[o*3+1]*Y + w_in[o*3+2]*Z + b_in[o];
  }
}

// ---------------------------------------------------------------------------
// kNN: 16 smallest (ties -> lower index), exact fp32 no-FMA replication of ref.
// BS=64 (one wave) -> more blocks/CU; __launch_bounds__(BS,1) -> full VGPR
// budget so the top-16 lists stay register-resident (round-3 spill fix).
template<int NK, int BS>
__global__ __launch_bounds__(BS,1) void knn_kernel(
    const float* __restrict__ qxyz, const float* __restrict__ kxyz,
    int Nq, int* __restrict__ oidx){
  __shared__ __align__(16) float4 kd[NK];
  int b = blockIdx.y, t = threadIdx.x;
  for (int i=t; i<NK; i+=BS){
    const float* p = kxyz + ((size_t)b*NK + i)*3;
    float X=p[0], Y=p[1], Z=p[2];
    float sk = __fadd_rn(__fadd_rn(__fmul_rn(X,X),__fmul_rn(Y,Y)),__fmul_rn(Z,Z));
    kd[i] = make_float4(X,Y,Z,sk);
  }
  __syncthreads();
  int q = blockIdx.x*BS + t;
  if (q >= Nq) return;
  const float* qp = qxyz + ((size_t)b*Nq + q)*3;
  float QX=qp[0], QY=qp[1], QZ=qp[2];
  float sq = __fadd_rn(__fadd_rn(__fmul_rn(QX,QX),__fmul_rn(QY,QY)),__fmul_rn(QZ,QZ));
  float dl[16]; int il[16];
  #pragma unroll
  for (int j=0;j<16;++j){ dl[j]=3.4e38f; il[j]=-1; }
  for (int m=0; m<NK; m+=8){
    float d[8];
    #pragma unroll
    for (int j=0;j<8;++j){
      float4 c = kd[m+j];
      float dot = __fadd_rn(__fadd_rn(__fmul_rn(QX,c.x),__fmul_rn(QY,c.y)),__fmul_rn(QZ,c.z));
      d[j] = __fsub_rn(__fadd_rn(sq, c.w), __fmul_rn(2.0f,dot));
    }
    float dmin = fminf(fminf(fminf(d[0],d[1]),fminf(d[2],d[3])),
                       fminf(fminf(d[4],d[5]),fminf(d[6],d[7])));
    if (dmin < dl[15]){
      #pragma unroll
      for (int j=0;j<8;++j){
        float dj = d[j];
        if (dj < dl[15]){               // strict <: equal dist keeps earlier index
          dl[15]=dj; il[15]=m+j;
          #pragma unroll
          for (int s=15;s>0;--s){
            if (dl[s] < dl[s-1]){       // strict <: stable among equals
              float td=dl[s]; dl[s]=dl[s-1]; dl[s-1]=td;
              int   ti=il[s]; il[s]=il[s-1]; il[s-1]=ti;
            }
          }
        }
      }
    }
  }
  int* op = oidx + ((size_t)b*Nq + q)*16;
  #pragma unroll
  for (int j=0;j<16;++j) op[j]=il[j];
}

// ---------------------------------------------------------------------------
// FPS: exact fp32 no-FMA; one barrier per step (double-buffered wave slots),
// winner index carried in registers by every thread.
template<int NP,int G,int T>
__global__ __launch_bounds__(T) void fps_kernel(
    const float* __restrict__ xyz, int* __restrict__ oidx, float* __restrict__ oxyz){
  constexpr int PPT = NP/T, W = T/64;
  __shared__ float xl[NP*3];
  __shared__ float redv[2][W];
  __shared__ int   redi[2][W];
  int b = blockIdx.x, t = threadIdx.x;
  for (int i=t;i<NP;i+=T){
    const float* p = xyz + ((size_t)b*NP + i)*3;
    xl[i*3+0]=p[0]; xl[i*3+1]=p[1]; xl[i*3+2]=p[2];
  }
  __syncthreads();
  float px[PPT], py[PPT], pz[PPT], dist[PPT];
  #pragma unroll
  for (int i=0;i<PPT;++i){
    int gi = t + i*T;
    px[i]=xl[gi*3]; py[i]=xl[gi*3+1]; pz[i]=xl[gi*3+2];
    dist[i]=1e10f;
  }
  int Bi = 0;
  if (t==0){
    oidx[(size_t)b*G] = 0;
    oxyz[(size_t)b*G*3+0]=xl[0]; oxyz[(size_t)b*G*3+1]=xl[1]; oxyz[(size_t)b*G*3+2]=xl[2];
  }
  for (int g=1; g<G; ++g){
    float cx=xl[3*Bi], cy=xl[3*Bi+1], cz=xl[3*Bi+2];
    float bv=-1.f; int bix=0;
    #pragma unroll
    for (int i=0;i<PPT;++i){
      float dx=__fsub_rn(px[i],cx), dy=__fsub_rn(py[i],cy), dz=__fsub_rn(pz[i],cz);
      float d = __fadd_rn(__fadd_rn(__fmul_rn(dx,dx),__fmul_rn(dy,dy)),__fmul_rn(dz,dz));
      float nd = fminf(dist[i], d);
      dist[i]=nd;
      int gi = t + i*T;
      if (nd > bv || (nd==bv && gi<bix)) { bv=nd; bix=gi; }
    }
    #pragma unroll
    for (int off=32; off>0; off>>=1){
      float ov = __shfl_down(bv, off);
      int   oi = __shfl_down(bix, off);
      if (ov > bv || (ov==bv && oi<bix)){ bv=ov; bix=oi; }
    }
    int par = g & 1;
    if ((t&63)==0){ redv[par][t>>6]=bv; redi[par][t>>6]=bix; }
    __syncthreads();
    float Bv = redv[par][0]; Bi = redi[par][0];
    #pragma unroll
    for (int wv=1; wv<W; ++wv){
      float rv = redv[par][wv]; int ri = redi[par][wv];
      if (rv > Bv || (rv==Bv && ri<Bi)){ Bv=rv; Bi=ri; }
    }
    if (t==0){
      oidx[(size_t)b*G + g] = Bi;
      float* op = oxyz + ((size_t)b*G + g)*3;
      op[0]=xl[3*Bi]; op[1]=xl[3*Bi+1]; op[2]=xl[3*Bi+2];
    }
  }
}

// ---------------------------------------------------------------------------
// EdgeConv pre-norm, query-batched. Block: QB queries, 256 threads, thread owns
// (ql, o, o+COUT/2) and ALL 16 k's. Key identity: the xq half of the edge
// feature is k-invariant, so y[o,k] = sum_{c<CF} w1[o,c]*nbr[c,k] + z[o],
// z = sum_c (w2[o,c]-w1[o,c])*fq[c]. Weights staged per CF-half (LDS <= 52KB).
// Stats: thread -> LDS atomic (8 floats) -> 8-way bucketed global atomics.
template<int CF,int COUT,int QB>
__global__ __launch_bounds__(256) void edge_kernel(
    const float* __restrict__ fk, const int* __restrict__ sel,
    const int* __restrict__ knn, const float* __restrict__ w,
    float* __restrict__ mm, float* __restrict__ stats, int Nq, int Nk){
  constexpr int CIN = 2*CF;
  constexpr int GPQ = COUT/2;        // threads per query (2 outputs/thread)
  constexpr int WS  = COUT+1;        // padded weight stride (conflict-free stage)
  constexpr int ESTR= CF*16+8;       // per-query e stride (+8 staggers banks)
  static_assert(QB*GPQ == 256, "block mapping");
  __shared__ float wtb[CF*WS];
  __shared__ __align__(16) float e[QB*ESTR];
  __shared__ float fqs[QB*CF];
  __shared__ float sS[8];            // [0..3]=sum per group, [4..7]=sumsq
  int b = blockIdx.y, t = threadIdx.x;
  int q0 = blockIdx.x*QB;

  if (t<8) sS[t]=0.f;
  for (int i=t; i<QB*CF; i+=256){
    int ql = i/CF, c = i&(CF-1);
    int qi = sel ? sel[b*Nq + q0 + ql] : (q0 + ql);
    fqs[i] = fk[((size_t)b*Nk + qi)*CF + c];
  }
  for (int i=t; i<CF*COUT; i+=256){
    int o = i/CF, c = i&(CF-1);
    wtb[c*WS+o] = w[o*CIN + c];
  }
  if (t < QB*16){
    int ql = t>>4, k = t&15;
    int nid = knn[((size_t)b*Nq + q0 + ql)*16 + k];
    const float4* row = (const float4*)(fk + ((size_t)b*Nk + nid)*CF);
    float* ep = e + ql*ESTR + k;
    #pragma unroll
    for (int c4=0; c4<CF/4; ++c4){
      float4 v = row[c4];
      ep[(c4*4+0)*16]=v.x; ep[(c4*4+1)*16]=v.y; ep[(c4*4+2)*16]=v.z; ep[(c4*4+3)*16]=v.w;
    }
  }
  __syncthreads();

  int ql = t/GPQ, o = t%GPQ;
  const float* eb = e + ql*ESTR;
  const float* fqb = fqs + ql*CF;
  float y0[16], y1[16];
  #pragma unroll
  for (int k=0;k<16;++k){ y0[k]=0.f; y1[k]=0.f; }
  float zA0=0.f, zA1=0.f;
  for (int c=0;c<CF;++c){
    float w0 = wtb[c*WS+o];
    float w1 = wtb[c*WS+o+GPQ];
    float fqc = fqb[c];
    zA0 = fmaf(w0,fqc,zA0); zA1 = fmaf(w1,fqc,zA1);
    const float4* ev4 = (const float4*)(eb + c*16);
    #pragma unroll
    for (int k4=0;k4<4;++k4){
      float4 ev = ev4[k4];
      y0[k4*4+0]=fmaf(w0,ev.x,y0[k4*4+0]); y0[k4*4+1]=fmaf(w0,ev.y,y0[k4*4+1]);
      y0[k4*4+2]=fmaf(w0,ev.z,y0[k4*4+2]); y0[k4*4+3]=fmaf(w0,ev.w,y0[k4*4+3]);
      y1[k4*4+0]=fmaf(w1,ev.x,y1[k4*4+0]); y1[k4*4+1]=fmaf(w1,ev.y,y1[k4*4+1]);
      y1[k4*4+2]=fmaf(w1,ev.z,y1[k4*4+2]); y1[k4*4+3]=fmaf(w1,ev.w,y1[k4*4+3]);
    }
  }
  __syncthreads();
  for (int i=t; i<CF*COUT; i+=256){
    int oo = i/CF, c = i&(CF-1);
    wtb[c*WS+oo] = w[oo*CIN + CF + c];
  }
  __syncthreads();
  float zB0=0.f, zB1=0.f;
  for (int c=0;c<CF;++c){
    float fqc = fqb[c];
    zB0 = fmaf(wtb[c*WS+o],fqc,zB0);
    zB1 = fmaf(wtb[c*WS+o+GPQ],fqc,zB1);
  }
  float z0 = zB0 - zA0, z1 = zB1 - zA1;

  float mx0=-3.4e38f, mn0=3.4e38f, s0=0.f, q0s=0.f;
  float mx1=-3.4e38f, mn1=3.4e38f, s1=0.f, q1s=0.f;
  #pragma unroll
  for (int k=0;k<16;++k){
    float v0 = y0[k]+z0, v1 = y1[k]+z1;
    mx0=fmaxf(mx0,v0); mn0=fminf(mn0,v0); s0+=v0; q0s=fmaf(v0,v0,q0s);
    mx1=fmaxf(mx1,v1); mn1=fminf(mn1,v1); s1+=v1; q1s=fmaf(v1,v1,q1s);
  }
  int g0 = o/(COUT/4);               // in {0,1}; second output is g0+2
  atomicAdd(&sS[g0],   s0); atomicAdd(&sS[4+g0],   q0s);
  atomicAdd(&sS[g0+2], s1); atomicAdd(&sS[6+g0],   q1s);
  size_t mi0 = ((size_t)b*Nq + q0 + ql)*COUT + o;
  ((float2*)mm)[mi0]       = make_float2(mx0,mn0);
  ((float2*)mm)[mi0+GPQ]   = make_float2(mx1,mn1);
  __syncthreads();
  if (t<8){
    int g = t>>1, which = t&1;
    float val = which ? sS[4+g] : sS[g];
    atomicAdd(&stats[(((size_t)b*4+g)*8 + (blockIdx.x&7))*2 + which], val);
  }
}

// ---------------------------------------------------------------------------
// finalize: sum stat buckets, GN affine on max (min if a<0) + LeakyReLU.
__global__ __launch_bounds__(256) void fin_kernel(
    const float* __restrict__ mm, const float* __restrict__ stats,
    const float* __restrict__ gam, const float* __restrict__ bet,
    float* __restrict__ fo, void* __restrict__ outbase, const int* __restrict__ flag,
    int outoff, int Nq, int COUT, float invcnt, int total){
  for (int i = blockIdx.x*256 + threadIdx.x; i<total; i += gridDim.x*256){
    int o = i % COUT;
    int r = i / COUT;
    int q = r % Nq;
    int b = r / Nq;
    int g = o / (COUT>>2);
    const float* sp = stats + ((size_t)(b*4+g))*16;
    float s=0.f, s2=0.f;
    #pragma unroll
    for (int nb=0;nb<8;++nb){ s += sp[nb*2]; s2 += sp[nb*2+1]; }
    float mean = s*invcnt;
    float var  = fmaxf(s2*invcnt - mean*mean, 0.f);
    float inv  = 1.0f / sqrtf(var + 1e-5f);
    float a  = gam[o] * inv;
    float bb = bet[o] - a*mean;
    const float* mp = mm + (size_t)i*2;
    float xv = (a>=0.f) ? mp[0] : mp[1];  // monotone affine: max commutes
    float v = fmaf(a, xv, bb);
    v = (v>=0.f) ? v : 0.2f*v;
    if (fo) fo[i]=v;
    if (outbase){
      int idx = outoff + ((b*COUT + o)*Nq + q);
      if (*flag) ((float*)outbase)[idx] = v;
      else       ((unsigned short*)outbase)[idx] = f2bf(v);
    }
  }
}

__global__ __launch_bounds__(256) void coor_kernel(
    const float* __restrict__ xyz2, void* __restrict__ outbase,
    const int* __restrict__ flag){
  int i = blockIdx.x*256+threadIdx.x;   // 32*3*128
  int m = i & 127;
  int c = (i>>7) % 3;
  int b = i / 384;
  float v = xyz2[((size_t)b*128+m)*3 + c];
  if (*flag) ((float*)outbase)[i] = v;
  else       ((unsigned short*)outbase)[i] = f2bf(v);
}

// ---------------------------------------------------------------------------
extern "C" void kernel_launch(void* const* d_in, const int* in_sizes, int n_in,
                              void* d_out, int out_size, void* d_ws, size_t ws_size,
                              hipStream_t stream){
  float* W    = (float*)d_ws;
  float* xyz0 = W;                      // 196608
  float* f0   = W + 196608;             // 524288
  float* f1   = W + 720896;             // 2097152
  float* xyz1 = W + 2818048;            // 49152
  float* f2   = W + 2867200;            // 1048576
  float* f3   = W + 3915776;            // 1048576
  float* xyz2 = W + 4964352;            // 12288
  float* stats= W + 4976640;            // 8192 (4 layers x 32 x 4 x 8buckets x 2)
  int*   flag = (int*)(W + 4984832);    // 16 (pad)
  float* PRM  = W + 4984848;            // 29792 canonical fp32 params
  int*  idx1  = (int*)(W + 5014640);    // 16384
  int*  idx2  = (int*)(W + 5031024);    // 4096
  float* SCR  = W + 5035120;            // aliased per-layer scratch
  int*   knnb = (int*)SCR;              // <= 1048576 ints
  float* mmb  = SCR + 1048576;          // <= 4194304 floats
  // total ~ 41.1 MB

  float* cw_in = PRM;          // 24
  float* cb_in = PRM+24;       // 8
  float* cw1 = PRM+32;   float* cg1 = PRM+544;   float* cbb1 = PRM+576;   // 512,32,32
  float* cw2 = PRM+608;  float* cg2 = PRM+4704;  float* cbb2 = PRM+4768;  // 4096,64,64
  float* cw3 = PRM+4832; float* cg3 = PRM+13024; float* cbb3 = PRM+13088; // 8192,64,64
  float* cw4 = PRM+13152;float* cg4 = PRM+29536; float* cbb4 = PRM+29664; // 16384,128,128

  detect_kernel<<<1,256,0,stream>>>((const unsigned short*)d_in[0], flag);

  PConv pc;
  const int psz[14] = {24,8,512,32,32,4096,64,64,8192,64,64,16384,128,128};
  float* pdst[14] = {cw_in,cb_in,cw1,cg1,cbb1,cw2,cg2,cbb2,cw3,cg3,cbb3,cw4,cg4,cbb4};
  for (int j=0;j<14;++j){ pc.s[j]=d_in[j+1]; pc.d[j]=pdst[j]; pc.sz[j]=psz[j]; }
  conv_params_kernel<<<117,256,0,stream>>>(pc, flag);

  prep_kernel<<<256,256,0,stream>>>(d_in[0], flag, cw_in, cb_in, xyz0, f0, stats);

  // ---- layer 1: 2048q/2048k, 16 -> 32
  knn_kernel<2048,64><<<dim3(32,32),64,0,stream>>>(xyz0, xyz0, 2048, knnb);
  edge_kernel<8,32,16><<<dim3(128,32),256,0,stream>>>(f0, nullptr, knnb, cw1, mmb, stats+0, 2048, 2048);
  fin_kernel<<<1024,256,0,stream>>>(mmb, stats+0, cg1, cbb1, f1, nullptr, flag, 0, 2048, 32, 1.f/262144.f, 2097152);

  // ---- FPS 2048 -> 512
  fps_kernel<2048,512,512><<<32,512,0,stream>>>(xyz0, idx1, xyz1);

  // ---- layer 2: 512q/2048k, 64 -> 64 (queries gathered via idx1)
  knn_kernel<2048,64><<<dim3(8,32),64,0,stream>>>(xyz1, xyz0, 512, knnb);
  edge_kernel<32,64,8><<<dim3(64,32),256,0,stream>>>(f1, idx1, knnb, cw2, mmb, stats+2048, 512, 2048);
  fin_kernel<<<1024,256,0,stream>>>(mmb, stats+2048, cg2, cbb2, f2, nullptr, flag, 0, 512, 64, 1.f/131072.f, 1048576);

  // ---- layer 3: 512q/512k, 128 -> 64
  knn_kernel<512,64><<<dim3(8,32),64,0,stream>>>(xyz1, xyz1, 512, knnb);
  edge_kernel<64,64,8><<<dim3(64,32),256,0,stream>>>(f2, nullptr, knnb, cw3, mmb, stats+4096, 512, 512);
  fin_kernel<<<1024,256,0,stream>>>(mmb, stats+4096, cg3, cbb3, f3, nullptr, flag, 0, 512, 64, 1.f/131072.f, 1048576);

  // ---- FPS 512 -> 128
  fps_kernel<512,128,512><<<32,512,0,stream>>>(xyz1, idx2, xyz2);

  // ---- layer 4: 128q/512k, 128 -> 128 (queries via idx2) -> final f output
  knn_kernel<512,64><<<dim3(2,32),64,0,stream>>>(xyz2, xyz1, 128, knnb);
  edge_kernel<64,128,4><<<dim3(32,32),256,0,stream>>>(f3, idx2, knnb, cw4, mmb, stats+6144, 128, 512);
  fin_kernel<<<1024,256,0,stream>>>(mmb, stats+6144, cg4, cbb4, nullptr, d_out, flag, 12288, 128, 128, 1.f/65536.f, 524288);

  // ---- coor output (B,3,128)
  coor_kernel<<<48,256,0,stream>>>(xyz2, d_out, flag);
}

// Round 5
// 1581.628 us; speedup vs baseline: 3.9965x; 1.6714x over previous
//
#include <hip/hip_runtime.h>
#include <hip/hip_bf16.h>

#define DEV __device__ __forceinline__

DEV float bf2f(unsigned short u){ return __uint_as_float(((unsigned)u)<<16); }
DEV unsigned short f2bf(float f){
  unsigned u = __float_as_uint(f);
  u += 0x7fffu + ((u>>16)&1u);   // RNE
  return (unsigned short)(u>>16);
}

// ---------------------------------------------------------------------------
// dtype detection: genuine bf16 N(0,1) data never has exponent >= 0xC0;
// fp32 read as ushorts has ~25% such halfwords. flag=1 -> inputs fp32.
__global__ __launch_bounds__(256) void detect_kernel(
    const unsigned short* __restrict__ x, int* __restrict__ flag){
  __shared__ int cnt;
  if (threadIdx.x==0) cnt = 0;
  __syncthreads();
  int local = 0;
  for (int i=threadIdx.x; i<4096; i+=256){
    int e = (x[i]>>7)&0xFF;
    if (e >= 0xC0) local++;
  }
  atomicAdd(&cnt, local);
  __syncthreads();
  if (threadIdx.x==0) *flag = (cnt > 64) ? 1 : 0;
}

// ---------------------------------------------------------------------------
struct PConv {
  const void* s[14];
  float*      d[14];
  int         sz[14];
};
__global__ __launch_bounds__(256) void conv_params_kernel(PConv p, const int* __restrict__ flag){
  bool isf = (*flag != 0);
  int i = blockIdx.x*256 + threadIdx.x;
  int seg = 0, off = i;
  #pragma unroll
  for (seg=0; seg<14; ++seg){
    if (off < p.sz[seg]) break;
    off -= p.sz[seg];
  }
  if (seg >= 14) return;
  float v = isf ? ((const float*)p.s[seg])[off]
                : bf2f(((const unsigned short*)p.s[seg])[off]);
  p.d[seg][off] = v;
}

// ---------------------------------------------------------------------------
// prep: coords (B,3,2048)->(B,2048,3) fp32, f0 = w_in@x + b_in, zero stats(8192).
__global__ __launch_bounds__(256) void prep_kernel(
    const void* __restrict__ xraw, const int* __restrict__ flag,
    const float* __restrict__ w_in, const float* __restrict__ b_in,
    float* __restrict__ xyz0, float* __restrict__ f0, float* __restrict__ stats){
  int i = blockIdx.x*256 + threadIdx.x;          // 32*2048 threads
  if (i < 8192) stats[i] = 0.f;
  bool isf = (*flag != 0);
  int b = i >> 11, n = i & 2047;
  size_t base = (size_t)b*3*2048 + n;
  float X, Y, Z;
  if (isf){
    const float* xf = (const float*)xraw;
    X = xf[base]; Y = xf[base+2048]; Z = xf[base+4096];
  } else {
    const unsigned short* xu = (const unsigned short*)xraw;
    X = bf2f(xu[base]); Y = bf2f(xu[base+2048]); Z = bf2f(xu[base+4096]);
  }
  float* o3 = xyz0 + (size_t)i*3;
  o3[0]=X; o3[1]=Y; o3[2]=Z;
  float* fo = f0 + (size_t)i*8;
  #pragma unroll
  for (int o=0;o<8;++o){
    fo[o] = w_in[o*3+0]*X + w_in[o*3+1]*Y + w_in[o*3+2]*Z + b_in[o];
  }
}

// ---------------------------------------------------------------------------
// Split-K kNN: 4 threads per query, thread h scans candidates m == h (mod 4)
// keeping a private sorted top-16 (strict-< insert => stable by index).
// Then a per-query leader 4-way merges the sorted lists by lex (d, idx) --
// exactly top_k's tie-by-lower-index semantics. kd LDS is reused for the
// merge lists (stride 65 floats per query kills the 64-way bank conflict).
template<int NK, int QB>
__global__ __launch_bounds__(QB*4, 4) void knn_kernel(
    const float* __restrict__ qxyz, const float* __restrict__ kxyz,
    int Nq, int* __restrict__ oidx){
  constexpr int BS = QB*4;
  constexpr int SM = (NK*4 > 130*QB) ? NK*4 : 130*QB;
  __shared__ __align__(16) float smem[SM];
  float4* kd = (float4*)smem;
  int b = blockIdx.y, t = threadIdx.x;
  for (int i=t; i<NK; i+=BS){
    const float* p = kxyz + ((size_t)b*NK + i)*3;
    float X=p[0], Y=p[1], Z=p[2];
    float sk = __fadd_rn(__fadd_rn(__fmul_rn(X,X),__fmul_rn(Y,Y)),__fmul_rn(Z,Z));
    kd[i] = make_float4(X,Y,Z,sk);
  }
  __syncthreads();
  int ql = t>>2, h = t&3;
  int q0 = blockIdx.x*QB;
  const float* qp = qxyz + ((size_t)b*Nq + q0 + ql)*3;
  float QX=qp[0], QY=qp[1], QZ=qp[2];
  float sq = __fadd_rn(__fadd_rn(__fmul_rn(QX,QX),__fmul_rn(QY,QY)),__fmul_rn(QZ,QZ));
  float dl[16]; int il[16];
  #pragma unroll
  for (int j=0;j<16;++j){ dl[j]=3.4e38f; il[j]=-1; }
  for (int i=0; i<NK/4; i+=8){
    float d[8];
    #pragma unroll
    for (int u=0;u<8;++u){
      float4 c = kd[4*(i+u)+h];
      float dot = __fadd_rn(__fadd_rn(__fmul_rn(QX,c.x),__fmul_rn(QY,c.y)),__fmul_rn(QZ,c.z));
      d[u] = __fsub_rn(__fadd_rn(sq, c.w), __fmul_rn(2.0f,dot));
    }
    float dmin = fminf(fminf(fminf(d[0],d[1]),fminf(d[2],d[3])),
                       fminf(fminf(d[4],d[5]),fminf(d[6],d[7])));
    if (dmin < dl[15]){
      #pragma unroll
      for (int u=0;u<8;++u){
        float du = d[u];
        if (du < dl[15]){               // strict <: equal dist keeps earlier index
          dl[15]=du; il[15]=4*(i+u)+h;
          #pragma unroll
          for (int s=15;s>0;--s){
            if (dl[s] < dl[s-1]){       // strict <: stable among equals
              float td=dl[s]; dl[s]=dl[s-1]; dl[s-1]=td;
              int   ti=il[s]; il[s]=il[s-1]; il[s-1]=ti;
            }
          }
        }
      }
    }
  }
  __syncthreads();                       // kd reads done; reuse smem for lists
  float* dbuf = smem;
  int*   ibuf = (int*)(smem + QB*65);
  int base = ql*65 + h*16;
  #pragma unroll
  for (int j=0;j<16;++j){ dbuf[base+j]=dl[j]; ibuf[base+j]=il[j]; }
  __syncthreads();
  if (t < QB){
    const float* db = dbuf + t*65;
    const int*   ib = ibuf + t*65;
    int p0=0,p1=0,p2=0,p3=0;
    int* op = oidx + ((size_t)b*Nq + q0 + t)*16;
    #pragma unroll 1
    for (int j=0;j<16;++j){
      float e0 = (p0<16)? db[p0]    : 3.5e38f; int i0 = (p0<16)? ib[p0]    : 0x7fffffff;
      float e1 = (p1<16)? db[16+p1] : 3.5e38f; int i1 = (p1<16)? ib[16+p1] : 0x7fffffff;
      float e2 = (p2<16)? db[32+p2] : 3.5e38f; int i2 = (p2<16)? ib[32+p2] : 0x7fffffff;
      float e3 = (p3<16)? db[48+p3] : 3.5e38f; int i3 = (p3<16)? ib[48+p3] : 0x7fffffff;
      float bd=e0; int bi=i0; int bh=0;
      if (e1<bd || (e1==bd && i1<bi)){ bd=e1; bi=i1; bh=1; }
      if (e2<bd || (e2==bd && i2<bi)){ bd=e2; bi=i2; bh=2; }
      if (e3<bd || (e3==bd && i3<bi)){ bd=e3; bi=i3; bh=3; }
      op[j]=bi;
      p0 += (bh==0); p1 += (bh==1); p2 += (bh==2); p3 += (bh==3);
    }
  }
}

// ---------------------------------------------------------------------------
// FPS: exact fp32 no-FMA; one barrier per step (double-buffered wave slots),
// winner index carried in registers by every thread.
template<int NP,int G,int T>
__global__ __launch_bounds__(T) void fps_kernel(
    const float* __restrict__ xyz, int* __restrict__ oidx, float* __restrict__ oxyz){
  constexpr int PPT = NP/T, W = T/64;
  __shared__ float xl[NP*3];
  __shared__ float redv[2][W];
  __shared__ int   redi[2][W];
  int b = blockIdx.x, t = threadIdx.x;
  for (int i=t;i<NP;i+=T){
    const float* p = xyz + ((size_t)b*NP + i)*3;
    xl[i*3+0]=p[0]; xl[i*3+1]=p[1]; xl[i*3+2]=p[2];
  }
  __syncthreads();
  float px[PPT], py[PPT], pz[PPT], dist[PPT];
  #pragma unroll
  for (int i=0;i<PPT;++i){
    int gi = t + i*T;
    px[i]=xl[gi*3]; py[i]=xl[gi*3+1]; pz[i]=xl[gi*3+2];
    dist[i]=1e10f;
  }
  int Bi = 0;
  if (t==0){
    oidx[(size_t)b*G] = 0;
    oxyz[(size_t)b*G*3+0]=xl[0]; oxyz[(size_t)b*G*3+1]=xl[1]; oxyz[(size_t)b*G*3+2]=xl[2];
  }
  for (int g=1; g<G; ++g){
    float cx=xl[3*Bi], cy=xl[3*Bi+1], cz=xl[3*Bi+2];
    float bv=-1.f; int bix=0;
    #pragma unroll
    for (int i=0;i<PPT;++i){
      float dx=__fsub_rn(px[i],cx), dy=__fsub_rn(py[i],cy), dz=__fsub_rn(pz[i],cz);
      float d = __fadd_rn(__fadd_rn(__fmul_rn(dx,dx),__fmul_rn(dy,dy)),__fmul_rn(dz,dz));
      float nd = fminf(dist[i], d);
      dist[i]=nd;
      int gi = t + i*T;
      if (nd > bv || (nd==bv && gi<bix)) { bv=nd; bix=gi; }
    }
    #pragma unroll
    for (int off=32; off>0; off>>=1){
      float ov = __shfl_down(bv, off);
      int   oi = __shfl_down(bix, off);
      if (ov > bv || (ov==bv && oi<bix)){ bv=ov; bix=oi; }
    }
    int par = g & 1;
    if ((t&63)==0){ redv[par][t>>6]=bv; redi[par][t>>6]=bix; }
    __syncthreads();
    float Bv = redv[par][0]; Bi = redi[par][0];
    #pragma unroll
    for (int wv=1; wv<W; ++wv){
      float rv = redv[par][wv]; int ri = redi[par][wv];
      if (rv > Bv || (rv==Bv && ri<Bi)){ Bv=rv; Bi=ri; }
    }
    if (t==0){
      oidx[(size_t)b*G + g] = Bi;
      float* op = oxyz + ((size_t)b*G + g)*3;
      op[0]=xl[3*Bi]; op[1]=xl[3*Bi+1]; op[2]=xl[3*Bi+2];
    }
  }
}

// ---------------------------------------------------------------------------
// EdgeConv pre-norm, query-batched. Block: QB queries, 256 threads, thread owns
// (ql, o, o+COUT/2) and ALL 16 k's. Key identity: the xq half of the edge
// feature is k-invariant, so y[o,k] = sum_{c<CF} w1[o,c]*nbr[c,k] + z[o],
// z = sum_c (w2[o,c]-w1[o,c])*fq[c]. Weights staged per CF-half (LDS <= 52KB).
// Stats: thread -> LDS atomic (8 floats) -> 8-way bucketed global atomics.
template<int CF,int COUT,int QB>
__global__ __launch_bounds__(256) void edge_kernel(
    const float* __restrict__ fk, const int* __restrict__ sel,
    const int* __restrict__ knn, const float* __restrict__ w,
    float* __restrict__ mm, float* __restrict__ stats, int Nq, int Nk){
  constexpr int CIN = 2*CF;
  constexpr int GPQ = COUT/2;        // threads per query (2 outputs/thread)
  constexpr int WS  = COUT+1;        // padded weight stride (conflict-free stage)
  constexpr int ESTR= CF*16+8;       // per-query e stride (+8 staggers banks)
  static_assert(QB*GPQ == 256, "block mapping");
  __shared__ float wtb[CF*WS];
  __shared__ __align__(16) float e[QB*ESTR];
  __shared__ float fqs[QB*CF];
  __shared__ float sS[8];            // [0..3]=sum per group, [4..7]=sumsq
  int b = blockIdx.y, t = threadIdx.x;
  int q0 = blockIdx.x*QB;

  if (t<8) sS[t]=0.f;
  for (int i=t; i<QB*CF; i+=256){
    int ql = i/CF, c = i&(CF-1);
    int qi = sel ? sel[b*Nq + q0 + ql] : (q0 + ql);
    fqs[i] = fk[((size_t)b*Nk + qi)*CF + c];
  }
  for (int i=t; i<CF*COUT; i+=256){
    int o = i/CF, c = i&(CF-1);
    wtb[c*WS+o] = w[o*CIN + c];
  }
  if (t < QB*16){
    int ql = t>>4, k = t&15;
    int nid = knn[((size_t)b*Nq + q0 + ql)*16 + k];
    const float4* row = (const float4*)(fk + ((size_t)b*Nk + nid)*CF);
    float* ep = e + ql*ESTR + k;
    #pragma unroll
    for (int c4=0; c4<CF/4; ++c4){
      float4 v = row[c4];
      ep[(c4*4+0)*16]=v.x; ep[(c4*4+1)*16]=v.y; ep[(c4*4+2)*16]=v.z; ep[(c4*4+3)*16]=v.w;
    }
  }
  __syncthreads();

  int ql = t/GPQ, o = t%GPQ;
  const float* eb = e + ql*ESTR;
  const float* fqb = fqs + ql*CF;
  float y0[16], y1[16];
  #pragma unroll
  for (int k=0;k<16;++k){ y0[k]=0.f; y1[k]=0.f; }
  float zA0=0.f, zA1=0.f;
  for (int c=0;c<CF;++c){
    float w0 = wtb[c*WS+o];
    float w1 = wtb[c*WS+o+GPQ];
    float fqc = fqb[c];
    zA0 = fmaf(w0,fqc,zA0); zA1 = fmaf(w1,fqc,zA1);
    const float4* ev4 = (const float4*)(eb + c*16);
    #pragma unroll
    for (int k4=0;k4<4;++k4){
      float4 ev = ev4[k4];
      y0[k4*4+0]=fmaf(w0,ev.x,y0[k4*4+0]); y0[k4*4+1]=fmaf(w0,ev.y,y0[k4*4+1]);
      y0[k4*4+2]=fmaf(w0,ev.z,y0[k4*4+2]); y0[k4*4+3]=fmaf(w0,ev.w,y0[k4*4+3]);
      y1[k4*4+0]=fmaf(w1,ev.x,y1[k4*4+0]); y1[k4*4+1]=fmaf(w1,ev.y,y1[k4*4+1]);
      y1[k4*4+2]=fmaf(w1,ev.z,y1[k4*4+2]); y1[k4*4+3]=fmaf(w1,ev.w,y1[k4*4+3]);
    }
  }
  __syncthreads();
  for (int i=t; i<CF*COUT; i+=256){
    int oo = i/CF, c = i&(CF-1);
    wtb[c*WS+oo] = w[oo*CIN + CF + c];
  }
  __syncthreads();
  float zB0=0.f, zB1=0.f;
  for (int c=0;c<CF;++c){
    float fqc = fqb[c];
    zB0 = fmaf(wtb[c*WS+o],fqc,zB0);
    zB1 = fmaf(wtb[c*WS+o+GPQ],fqc,zB1);
  }
  float z0 = zB0 - zA0, z1 = zB1 - zA1;

  float mx0=-3.4e38f, mn0=3.4e38f, s0=0.f, q0s=0.f;
  float mx1=-3.4e38f, mn1=3.4e38f, s1=0.f, q1s=0.f;
  #pragma unroll
  for (int k=0;k<16;++k){
    float v0 = y0[k]+z0, v1 = y1[k]+z1;
    mx0=fmaxf(mx0,v0); mn0=fminf(mn0,v0); s0+=v0; q0s=fmaf(v0,v0,q0s);
    mx1=fmaxf(mx1,v1); mn1=fminf(mn1,v1); s1+=v1; q1s=fmaf(v1,v1,q1s);
  }
  int g0 = o/(COUT/4);               // in {0,1}; second output is g0+2
  atomicAdd(&sS[g0],   s0); atomicAdd(&sS[4+g0],   q0s);
  atomicAdd(&sS[g0+2], s1); atomicAdd(&sS[6+g0],   q1s);
  size_t mi0 = ((size_t)b*Nq + q0 + ql)*COUT + o;
  ((float2*)mm)[mi0]       = make_float2(mx0,mn0);
  ((float2*)mm)[mi0+GPQ]   = make_float2(mx1,mn1);
  __syncthreads();
  if (t<8){
    int g = t>>1, which = t&1;
    float val = which ? sS[4+g] : sS[g];
    atomicAdd(&stats[(((size_t)b*4+g)*8 + (blockIdx.x&7))*2 + which], val);
  }
}

// ---------------------------------------------------------------------------
// finalize: sum stat buckets, GN affine on max (min if a<0) + LeakyReLU.
__global__ __launch_bounds__(256) void fin_kernel(
    const float* __restrict__ mm, const float* __restrict__ stats,
    const float* __restrict__ gam, const float* __restrict__ bet,
    float* __restrict__ fo, void* __restrict__ outbase, const int* __restrict__ flag,
    int outoff, int Nq, int COUT, float invcnt, int total){
  for (int i = blockIdx.x*256 + threadIdx.x; i<total; i += gridDim.x*256){
    int o = i % COUT;
    int r = i / COUT;
    int q = r % Nq;
    int b = r / Nq;
    int g = o / (COUT>>2);
    const float* sp = stats + ((size_t)(b*4+g))*16;
    float s=0.f, s2=0.f;
    #pragma unroll
    for (int nb=0;nb<8;++nb){ s += sp[nb*2]; s2 += sp[nb*2+1]; }
    float mean = s*invcnt;
    float var  = fmaxf(s2*invcnt - mean*mean, 0.f);
    float inv  = 1.0f / sqrtf(var + 1e-5f);
    float a  = gam[o] * inv;
    float bb = bet[o] - a*mean;
    const float* mp = mm + (size_t)i*2;
    float xv = (a>=0.f) ? mp[0] : mp[1];  // monotone affine: max commutes
    float v = fmaf(a, xv, bb);
    v = (v>=0.f) ? v : 0.2f*v;
    if (fo) fo[i]=v;
    if (outbase){
      int idx = outoff + ((b*COUT + o)*Nq + q);
      if (*flag) ((float*)outbase)[idx] = v;
      else       ((unsigned short*)outbase)[idx] = f2bf(v);
    }
  }
}

__global__ __launch_bounds__(256) void coor_kernel(
    const float* __restrict__ xyz2, void* __restrict__ outbase,
    const int* __restrict__ flag){
  int i = blockIdx.x*256+threadIdx.x;   // 32*3*128
  int m = i & 127;
  int c = (i>>7) % 3;
  int b = i / 384;
  float v = xyz2[((size_t)b*128+m)*3 + c];
  if (*flag) ((float*)outbase)[i] = v;
  else       ((unsigned short*)outbase)[i] = f2bf(v);
}

// ---------------------------------------------------------------------------
extern "C" void kernel_launch(void* const* d_in, const int* in_sizes, int n_in,
                              void* d_out, int out_size, void* d_ws, size_t ws_size,
                              hipStream_t stream){
  float* W    = (float*)d_ws;
  float* xyz0 = W;                      // 196608
  float* f0   = W + 196608;             // 524288
  float* f1   = W + 720896;             // 2097152
  float* xyz1 = W + 2818048;            // 49152
  float* f2   = W + 2867200;            // 1048576
  float* f3   = W + 3915776;            // 1048576
  float* xyz2 = W + 4964352;            // 12288
  float* stats= W + 4976640;            // 8192 (4 layers x 32 x 4 x 8buckets x 2)
  int*   flag = (int*)(W + 4984832);    // 16 (pad)
  float* PRM  = W + 4984848;            // 29792 canonical fp32 params
  int*  idx1  = (int*)(W + 5014640);    // 16384
  int*  idx2  = (int*)(W + 5031024);    // 4096
  float* SCR  = W + 5035120;            // aliased per-layer scratch
  int*   knnb = (int*)SCR;              // <= 1048576 ints
  float* mmb  = SCR + 1048576;          // <= 4194304 floats
  // total ~ 41.1 MB

  float* cw_in = PRM;          // 24
  float* cb_in = PRM+24;       // 8
  float* cw1 = PRM+32;   float* cg1 = PRM+544;   float* cbb1 = PRM+576;   // 512,32,32
  float* cw2 = PRM+608;  float* cg2 = PRM+4704;  float* cbb2 = PRM+4768;  // 4096,64,64
  float* cw3 = PRM+4832; float* cg3 = PRM+13024; float* cbb3 = PRM+13088; // 8192,64,64
  float* cw4 = PRM+13152;float* cg4 = PRM+29536; float* cbb4 = PRM+29664; // 16384,128,128

  detect_kernel<<<1,256,0,stream>>>((const unsigned short*)d_in[0], flag);

  PConv pc;
  const int psz[14] = {24,8,512,32,32,4096,64,64,8192,64,64,16384,128,128};
  float* pdst[14] = {cw_in,cb_in,cw1,cg1,cbb1,cw2,cg2,cbb2,cw3,cg3,cbb3,cw4,cg4,cbb4};
  for (int j=0;j<14;++j){ pc.s[j]=d_in[j+1]; pc.d[j]=pdst[j]; pc.sz[j]=psz[j]; }
  conv_params_kernel<<<117,256,0,stream>>>(pc, flag);

  prep_kernel<<<256,256,0,stream>>>(d_in[0], flag, cw_in, cb_in, xyz0, f0, stats);

  // ---- layer 1: 2048q/2048k, 16 -> 32
  knn_kernel<2048,64><<<dim3(32,32),256,0,stream>>>(xyz0, xyz0, 2048, knnb);
  edge_kernel<8,32,16><<<dim3(128,32),256,0,stream>>>(f0, nullptr, knnb, cw1, mmb, stats+0, 2048, 2048);
  fin_kernel<<<1024,256,0,stream>>>(mmb, stats+0, cg1, cbb1, f1, nullptr, flag, 0, 2048, 32, 1.f/262144.f, 2097152);

  // ---- FPS 2048 -> 512
  fps_kernel<2048,512,512><<<32,512,0,stream>>>(xyz0, idx1, xyz1);

  // ---- layer 2: 512q/2048k, 64 -> 64 (queries gathered via idx1)
  knn_kernel<2048,64><<<dim3(8,32),256,0,stream>>>(xyz1, xyz0, 512, knnb);
  edge_kernel<32,64,8><<<dim3(64,32),256,0,stream>>>(f1, idx1, knnb, cw2, mmb, stats+2048, 512, 2048);
  fin_kernel<<<1024,256,0,stream>>>(mmb, stats+2048, cg2, cbb2, f2, nullptr, flag, 0, 512, 64, 1.f/131072.f, 1048576);

  // ---- layer 3: 512q/512k, 128 -> 64
  knn_kernel<512,64><<<dim3(8,32),256,0,stream>>>(xyz1, xyz1, 512, knnb);
  edge_kernel<64,64,8><<<dim3(64,32),256,0,stream>>>(f2, nullptr, knnb, cw3, mmb, stats+4096, 512, 512);
  fin_kernel<<<1024,256,0,stream>>>(mmb, stats+4096, cg3, cbb3, f3, nullptr, flag, 0, 512, 64, 1.f/131072.f, 1048576);

  // ---- FPS 512 -> 128
  fps_kernel<512,128,512><<<32,512,0,stream>>>(xyz1, idx2, xyz2);

  // ---- layer 4: 128q/512k, 128 -> 128 (queries via idx2) -> final f output
  knn_kernel<512,64><<<dim3(2,32),256,0,stream>>>(xyz2, xyz1, 128, knnb);
  edge_kernel<64,128,4><<<dim3(32,32),256,0,stream>>>(f3, idx2, knnb, cw4, mmb, stats+6144, 128, 512);
  fin_kernel<<<1024,256,0,stream>>>(mmb, stats+6144, cg4, cbb4, nullptr, d_out, flag, 12288, 128, 128, 1.f/65536.f, 524288);

  // ---- coor output (B,3,128)
  coor_kernel<<<48,256,0,stream>>>(xyz2, d_out, flag);
}

// Round 6
// 1343.450 us; speedup vs baseline: 4.7051x; 1.1773x over previous
//
#include <hip/hip_runtime.h>
#include <hip/hip_bf16.h>

#define DEV __device__ __forceinline__

DEV float bf2f(unsigned short u){ return __uint_as_float(((unsigned)u)<<16); }
DEV unsigned short f2bf(float f){
  unsigned u = __float_as_uint(f);
  u += 0x7fffu + ((u>>16)&1u);   // RNE
  return (unsigned short)(u>>16);
}

// ---------------------------------------------------------------------------
// dtype detection: genuine bf16 N(0,1) data never has exponent >= 0xC0;
// fp32 read as ushorts has ~25% such halfwords. flag=1 -> inputs fp32.
__global__ __launch_bounds__(256) void detect_kernel(
    const unsigned short* __restrict__ x, int* __restrict__ flag){
  __shared__ int cnt;
  if (threadIdx.x==0) cnt = 0;
  __syncthreads();
  int local = 0;
  for (int i=threadIdx.x; i<4096; i+=256){
    int e = (x[i]>>7)&0xFF;
    if (e >= 0xC0) local++;
  }
  atomicAdd(&cnt, local);
  __syncthreads();
  if (threadIdx.x==0) *flag = (cnt > 64) ? 1 : 0;
}

// ---------------------------------------------------------------------------
struct PConv {
  const void* s[14];
  float*      d[14];
  int         sz[14];
};
__global__ __launch_bounds__(256) void conv_params_kernel(PConv p, const int* __restrict__ flag){
  bool isf = (*flag != 0);
  int i = blockIdx.x*256 + threadIdx.x;
  int seg = 0, off = i;
  #pragma unroll
  for (seg=0; seg<14; ++seg){
    if (off < p.sz[seg]) break;
    off -= p.sz[seg];
  }
  if (seg >= 14) return;
  float v = isf ? ((const float*)p.s[seg])[off]
                : bf2f(((const unsigned short*)p.s[seg])[off]);
  p.d[seg][off] = v;
}

// ---------------------------------------------------------------------------
// prep: coords (B,3,2048)->(B,2048,3) fp32, f0 = w_in@x + b_in, zero stats(8192).
__global__ __launch_bounds__(256) void prep_kernel(
    const void* __restrict__ xraw, const int* __restrict__ flag,
    const float* __restrict__ w_in, const float* __restrict__ b_in,
    float* __restrict__ xyz0, float* __restrict__ f0, float* __restrict__ stats){
  int i = blockIdx.x*256 + threadIdx.x;          // 32*2048 threads
  if (i < 8192) stats[i] = 0.f;
  bool isf = (*flag != 0);
  int b = i >> 11, n = i & 2047;
  size_t base = (size_t)b*3*2048 + n;
  float X, Y, Z;
  if (isf){
    const float* xf = (const float*)xraw;
    X = xf[base]; Y = xf[base+2048]; Z = xf[base+4096];
  } else {
    const unsigned short* xu = (const unsigned short*)xraw;
    X = bf2f(xu[base]); Y = bf2f(xu[base+2048]); Z = bf2f(xu[base+4096]);
  }
  float* o3 = xyz0 + (size_t)i*3;
  o3[0]=X; o3[1]=Y; o3[2]=Z;
  float* fo = f0 + (size_t)i*8;
  #pragma unroll
  for (int o=0;o<8;++o){
    fo[o] = w_in[o*3+0]*X + w_in[o*3+1]*Y + w_in[o*3+2]*Z + b_in[o];
  }
}

// ---------------------------------------------------------------------------
// Split-K kNN: 4 threads per query, thread h scans candidates m == h (mod 4)
// keeping a private sorted top-16 (strict-< insert => stable by index).
// Then a per-query leader 4-way merges the sorted lists by lex (d, idx) --
// exactly top_k's tie-by-lower-index semantics. kd LDS is reused for the
// merge lists (stride 65 floats per query kills the 64-way bank conflict).
template<int NK, int QB>
__global__ __launch_bounds__(QB*4, 4) void knn_kernel(
    const float* __restrict__ qxyz, const float* __restrict__ kxyz,
    int Nq, int* __restrict__ oidx){
  constexpr int BS = QB*4;
  constexpr int SM = (NK*4 > 130*QB) ? NK*4 : 130*QB;
  __shared__ __align__(16) float smem[SM];
  float4* kd = (float4*)smem;
  int b = blockIdx.y, t = threadIdx.x;
  for (int i=t; i<NK; i+=BS){
    const float* p = kxyz + ((size_t)b*NK + i)*3;
    float X=p[0], Y=p[1], Z=p[2];
    float sk = __fadd_rn(__fadd_rn(__fmul_rn(X,X),__fmul_rn(Y,Y)),__fmul_rn(Z,Z));
    kd[i] = make_float4(X,Y,Z,sk);
  }
  __syncthreads();
  int ql = t>>2, h = t&3;
  int q0 = blockIdx.x*QB;
  const float* qp = qxyz + ((size_t)b*Nq + q0 + ql)*3;
  float QX=qp[0], QY=qp[1], QZ=qp[2];
  float sq = __fadd_rn(__fadd_rn(__fmul_rn(QX,QX),__fmul_rn(QY,QY)),__fmul_rn(QZ,QZ));
  float dl[16]; int il[16];
  #pragma unroll
  for (int j=0;j<16;++j){ dl[j]=3.4e38f; il[j]=-1; }
  for (int i=0; i<NK/4; i+=8){
    float d[8];
    #pragma unroll
    for (int u=0;u<8;++u){
      float4 c = kd[4*(i+u)+h];
      float dot = __fadd_rn(__fadd_rn(__fmul_rn(QX,c.x),__fmul_rn(QY,c.y)),__fmul_rn(QZ,c.z));
      d[u] = __fsub_rn(__fadd_rn(sq, c.w), __fmul_rn(2.0f,dot));
    }
    float dmin = fminf(fminf(fminf(d[0],d[1]),fminf(d[2],d[3])),
                       fminf(fminf(d[4],d[5]),fminf(d[6],d[7])));
    if (dmin < dl[15]){
      #pragma unroll
      for (int u=0;u<8;++u){
        float du = d[u];
        if (du < dl[15]){               // strict <: equal dist keeps earlier index
          dl[15]=du; il[15]=4*(i+u)+h;
          #pragma unroll
          for (int s=15;s>0;--s){
            if (dl[s] < dl[s-1]){       // strict <: stable among equals
              float td=dl[s]; dl[s]=dl[s-1]; dl[s-1]=td;
              int   ti=il[s]; il[s]=il[s-1]; il[s-1]=ti;
            }
          }
        }
      }
    }
  }
  __syncthreads();                       // kd reads done; reuse smem for lists
  float* dbuf = smem;
  int*   ibuf = (int*)(smem + QB*65);
  int base = ql*65 + h*16;
  #pragma unroll
  for (int j=0;j<16;++j){ dbuf[base+j]=dl[j]; ibuf[base+j]=il[j]; }
  __syncthreads();
  if (t < QB){
    const float* db = dbuf + t*65;
    const int*   ib = ibuf + t*65;
    int p0=0,p1=0,p2=0,p3=0;
    int* op = oidx + ((size_t)b*Nq + q0 + t)*16;
    #pragma unroll 1
    for (int j=0;j<16;++j){
      float e0 = (p0<16)? db[p0]    : 3.5e38f; int i0 = (p0<16)? ib[p0]    : 0x7fffffff;
      float e1 = (p1<16)? db[16+p1] : 3.5e38f; int i1 = (p1<16)? ib[16+p1] : 0x7fffffff;
      float e2 = (p2<16)? db[32+p2] : 3.5e38f; int i2 = (p2<16)? ib[32+p2] : 0x7fffffff;
      float e3 = (p3<16)? db[48+p3] : 3.5e38f; int i3 = (p3<16)? ib[48+p3] : 0x7fffffff;
      float bd=e0; int bi=i0; int bh=0;
      if (e1<bd || (e1==bd && i1<bi)){ bd=e1; bi=i1; bh=1; }
      if (e2<bd || (e2==bd && i2<bi)){ bd=e2; bi=i2; bh=2; }
      if (e3<bd || (e3==bd && i3<bi)){ bd=e3; bi=i3; bh=3; }
      op[j]=bi;
      p0 += (bh==0); p1 += (bh==1); p2 += (bh==2); p3 += (bh==3);
    }
  }
}

// ---------------------------------------------------------------------------
// FPS: single 64-lane wave per batch, ZERO barriers in the serial loop.
// dist/coords register-resident; per-lane scan keeps first-max (strict >);
// XOR-butterfly on (val,idx) with lex (val desc, idx asc) compare == ref
// argmax tie-breaks (total order -> associative -> all lanes converge).
// Centroid via 3 broadcast LDS reads; lane0 global stores never block.
// Exact fp32 no-FMA arithmetic throughout.
template<int NP,int G>
__global__ __launch_bounds__(64,1) void fps_kernel(
    const float* __restrict__ xyz, int* __restrict__ oidx, float* __restrict__ oxyz){
  constexpr int PPT = NP/64;
  __shared__ float xl[NP*3];
  int b = blockIdx.x, t = threadIdx.x;
  float px[PPT], py[PPT], pz[PPT], dist[PPT];
  #pragma unroll
  for (int j=0;j<PPT;++j){
    int gi = t + j*64;
    const float* p = xyz + ((size_t)b*NP + gi)*3;
    float X=p[0], Y=p[1], Z=p[2];
    px[j]=X; py[j]=Y; pz[j]=Z; dist[j]=1e10f;
    xl[gi*3+0]=X; xl[gi*3+1]=Y; xl[gi*3+2]=Z;
  }
  __syncthreads();                       // one-time: xl visible to all lanes
  int Bi = 0;
  if (t==0){
    oidx[(size_t)b*G] = 0;
    float* op = oxyz + (size_t)b*G*3;
    op[0]=xl[0]; op[1]=xl[1]; op[2]=xl[2];
  }
  for (int g=1; g<G; ++g){
    float cx = xl[3*Bi], cy = xl[3*Bi+1], cz = xl[3*Bi+2];
    float bv = -1.f; int bi = 0x7fffffff;
    #pragma unroll
    for (int j=0;j<PPT;++j){
      float dx=__fsub_rn(px[j],cx), dy=__fsub_rn(py[j],cy), dz=__fsub_rn(pz[j],cz);
      float d = __fadd_rn(__fadd_rn(__fmul_rn(dx,dx),__fmul_rn(dy,dy)),__fmul_rn(dz,dz));
      float nd = fminf(dist[j], d);
      dist[j] = nd;
      // ascending gi within lane: strict > keeps first occurrence exactly
      bool c = (nd > bv);
      bv = c ? nd : bv;
      bi = c ? (t + j*64) : bi;
    }
    #pragma unroll
    for (int off=1; off<64; off<<=1){
      float ov = __shfl_xor(bv, off);
      int   oi = __shfl_xor(bi, off);
      bool c = (ov > bv) || (ov == bv && oi < bi);
      bv = c ? ov : bv;
      bi = c ? oi : bi;
    }
    Bi = bi;                             // identical in every lane
    if (t==0){
      oidx[(size_t)b*G + g] = Bi;
      float* op = oxyz + ((size_t)b*G + g)*3;
      op[0]=xl[3*Bi]; op[1]=xl[3*Bi+1]; op[2]=xl[3*Bi+2];
    }
  }
}

// ---------------------------------------------------------------------------
// EdgeConv pre-norm, query-batched. Block: QB queries, 256 threads, thread owns
// (ql, o, o+COUT/2) and ALL 16 k's. Key identity: the xq half of the edge
// feature is k-invariant, so y[o,k] = sum_{c<CF} w1[o,c]*nbr[c,k] + z[o],
// z = sum_c (w2[o,c]-w1[o,c])*fq[c]. Weights staged per CF-half (LDS <= 52KB).
// Stats: thread -> LDS atomic (8 floats) -> 8-way bucketed global atomics.
template<int CF,int COUT,int QB>
__global__ __launch_bounds__(256) void edge_kernel(
    const float* __restrict__ fk, const int* __restrict__ sel,
    const int* __restrict__ knn, const float* __restrict__ w,
    float* __restrict__ mm, float* __restrict__ stats, int Nq, int Nk){
  constexpr int CIN = 2*CF;
  constexpr int GPQ = COUT/2;        // threads per query (2 outputs/thread)
  constexpr int WS  = COUT+1;        // padded weight stride (conflict-free stage)
  constexpr int ESTR= CF*16+8;       // per-query e stride (+8 staggers banks)
  static_assert(QB*GPQ == 256, "block mapping");
  __shared__ float wtb[CF*WS];
  __shared__ __align__(16) float e[QB*ESTR];
  __shared__ float fqs[QB*CF];
  __shared__ float sS[8];            // [0..3]=sum per group, [4..7]=sumsq
  int b = blockIdx.y, t = threadIdx.x;
  int q0 = blockIdx.x*QB;

  if (t<8) sS[t]=0.f;
  for (int i=t; i<QB*CF; i+=256){
    int ql = i/CF, c = i&(CF-1);
    int qi = sel ? sel[b*Nq + q0 + ql] : (q0 + ql);
    fqs[i] = fk[((size_t)b*Nk + qi)*CF + c];
  }
  for (int i=t; i<CF*COUT; i+=256){
    int o = i/CF, c = i&(CF-1);
    wtb[c*WS+o] = w[o*CIN + c];
  }
  if (t < QB*16){
    int ql = t>>4, k = t&15;
    int nid = knn[((size_t)b*Nq + q0 + ql)*16 + k];
    const float4* row = (const float4*)(fk + ((size_t)b*Nk + nid)*CF);
    float* ep = e + ql*ESTR + k;
    #pragma unroll
    for (int c4=0; c4<CF/4; ++c4){
      float4 v = row[c4];
      ep[(c4*4+0)*16]=v.x; ep[(c4*4+1)*16]=v.y; ep[(c4*4+2)*16]=v.z; ep[(c4*4+3)*16]=v.w;
    }
  }
  __syncthreads();

  int ql = t/GPQ, o = t%GPQ;
  const float* eb = e + ql*ESTR;
  const float* fqb = fqs + ql*CF;
  float y0[16], y1[16];
  #pragma unroll
  for (int k=0;k<16;++k){ y0[k]=0.f; y1[k]=0.f; }
  float zA0=0.f, zA1=0.f;
  for (int c=0;c<CF;++c){
    float w0 = wtb[c*WS+o];
    float w1 = wtb[c*WS+o+GPQ];
    float fqc = fqb[c];
    zA0 = fmaf(w0,fqc,zA0); zA1 = fmaf(w1,fqc,zA1);
    const float4* ev4 = (const float4*)(eb + c*16);
    #pragma unroll
    for (int k4=0;k4<4;++k4){
      float4 ev = ev4[k4];
      y0[k4*4+0]=fmaf(w0,ev.x,y0[k4*4+0]); y0[k4*4+1]=fmaf(w0,ev.y,y0[k4*4+1]);
      y0[k4*4+2]=fmaf(w0,ev.z,y0[k4*4+2]); y0[k4*4+3]=fmaf(w0,ev.w,y0[k4*4+3]);
      y1[k4*4+0]=fmaf(w1,ev.x,y1[k4*4+0]); y1[k4*4+1]=fmaf(w1,ev.y,y1[k4*4+1]);
      y1[k4*4+2]=fmaf(w1,ev.z,y1[k4*4+2]); y1[k4*4+3]=fmaf(w1,ev.w,y1[k4*4+3]);
    }
  }
  __syncthreads();
  for (int i=t; i<CF*COUT; i+=256){
    int oo = i/CF, c = i&(CF-1);
    wtb[c*WS+oo] = w[oo*CIN + CF + c];
  }
  __syncthreads();
  float zB0=0.f, zB1=0.f;
  for (int c=0;c<CF;++c){
    float fqc = fqb[c];
    zB0 = fmaf(wtb[c*WS+o],fqc,zB0);
    zB1 = fmaf(wtb[c*WS+o+GPQ],fqc,zB1);
  }
  float z0 = zB0 - zA0, z1 = zB1 - zA1;

  float mx0=-3.4e38f, mn0=3.4e38f, s0=0.f, q0s=0.f;
  float mx1=-3.4e38f, mn1=3.4e38f, s1=0.f, q1s=0.f;
  #pragma unroll
  for (int k=0;k<16;++k){
    float v0 = y0[k]+z0, v1 = y1[k]+z1;
    mx0=fmaxf(mx0,v0); mn0=fminf(mn0,v0); s0+=v0; q0s=fmaf(v0,v0,q0s);
    mx1=fmaxf(mx1,v1); mn1=fminf(mn1,v1); s1+=v1; q1s=fmaf(v1,v1,q1s);
  }
  int g0 = o/(COUT/4);               // in {0,1}; second output is g0+2
  atomicAdd(&sS[g0],   s0); atomicAdd(&sS[4+g0],   q0s);
  atomicAdd(&sS[g0+2], s1); atomicAdd(&sS[6+g0],   q1s);
  size_t mi0 = ((size_t)b*Nq + q0 + ql)*COUT + o;
  ((float2*)mm)[mi0]       = make_float2(mx0,mn0);
  ((float2*)mm)[mi0+GPQ]   = make_float2(mx1,mn1);
  __syncthreads();
  if (t<8){
    int g = t>>1, which = t&1;
    float val = which ? sS[4+g] : sS[g];
    atomicAdd(&stats[(((size_t)b*4+g)*8 + (blockIdx.x&7))*2 + which], val);
  }
}

// ---------------------------------------------------------------------------
// finalize: sum stat buckets, GN affine on max (min if a<0) + LeakyReLU.
__global__ __launch_bounds__(256) void fin_kernel(
    const float* __restrict__ mm, const float* __restrict__ stats,
    const float* __restrict__ gam, const float* __restrict__ bet,
    float* __restrict__ fo, void* __restrict__ outbase, const int* __restrict__ flag,
    int outoff, int Nq, int COUT, float invcnt, int total){
  for (int i = blockIdx.x*256 + threadIdx.x; i<total; i += gridDim.x*256){
    int o = i % COUT;
    int r = i / COUT;
    int q = r % Nq;
    int b = r / Nq;
    int g = o / (COUT>>2);
    const float* sp = stats + ((size_t)(b*4+g))*16;
    float s=0.f, s2=0.f;
    #pragma unroll
    for (int nb=0;nb<8;++nb){ s += sp[nb*2]; s2 += sp[nb*2+1]; }
    float mean = s*invcnt;
    float var  = fmaxf(s2*invcnt - mean*mean, 0.f);
    float inv  = 1.0f / sqrtf(var + 1e-5f);
    float a  = gam[o] * inv;
    float bb = bet[o] - a*mean;
    const float* mp = mm + (size_t)i*2;
    float xv = (a>=0.f) ? mp[0] : mp[1];  // monotone affine: max commutes
    float v = fmaf(a, xv, bb);
    v = (v>=0.f) ? v : 0.2f*v;
    if (fo) fo[i]=v;
    if (outbase){
      int idx = outoff + ((b*COUT + o)*Nq + q);
      if (*flag) ((float*)outbase)[idx] = v;
      else       ((unsigned short*)outbase)[idx] = f2bf(v);
    }
  }
}

__global__ __launch_bounds__(256) void coor_kernel(
    const float* __restrict__ xyz2, void* __restrict__ outbase,
    const int* __restrict__ flag){
  int i = blockIdx.x*256+threadIdx.x;   // 32*3*128
  int m = i & 127;
  int c = (i>>7) % 3;
  int b = i / 384;
  float v = xyz2[((size_t)b*128+m)*3 + c];
  if (*flag) ((float*)outbase)[i] = v;
  else       ((unsigned short*)outbase)[i] = f2bf(v);
}

// ---------------------------------------------------------------------------
extern "C" void kernel_launch(void* const* d_in, const int* in_sizes, int n_in,
                              void* d_out, int out_size, void* d_ws, size_t ws_size,
                              hipStream_t stream){
  float* W    = (float*)d_ws;
  float* xyz0 = W;                      // 196608
  float* f0   = W + 196608;             // 524288
  float* f1   = W + 720896;             // 2097152
  float* xyz1 = W + 2818048;            // 49152
  float* f2   = W + 2867200;            // 1048576
  float* f3   = W + 3915776;            // 1048576
  float* xyz2 = W + 4964352;            // 12288
  float* stats= W + 4976640;            // 8192 (4 layers x 32 x 4 x 8buckets x 2)
  int*   flag = (int*)(W + 4984832);    // 16 (pad)
  float* PRM  = W + 4984848;            // 29792 canonical fp32 params
  int*  idx1  = (int*)(W + 5014640);    // 16384
  int*  idx2  = (int*)(W + 5031024);    // 4096
  float* SCR  = W + 5035120;            // aliased per-layer scratch
  int*   knnb = (int*)SCR;              // <= 1048576 ints
  float* mmb  = SCR + 1048576;          // <= 4194304 floats
  // total ~ 41.1 MB

  float* cw_in = PRM;          // 24
  float* cb_in = PRM+24;       // 8
  float* cw1 = PRM+32;   float* cg1 = PRM+544;   float* cbb1 = PRM+576;   // 512,32,32
  float* cw2 = PRM+608;  float* cg2 = PRM+4704;  float* cbb2 = PRM+4768;  // 4096,64,64
  float* cw3 = PRM+4832; float* cg3 = PRM+13024; float* cbb3 = PRM+13088; // 8192,64,64
  float* cw4 = PRM+13152;float* cg4 = PRM+29536; float* cbb4 = PRM+29664; // 16384,128,128

  detect_kernel<<<1,256,0,stream>>>((const unsigned short*)d_in[0], flag);

  PConv pc;
  const int psz[14] = {24,8,512,32,32,4096,64,64,8192,64,64,16384,128,128};
  float* pdst[14] = {cw_in,cb_in,cw1,cg1,cbb1,cw2,cg2,cbb2,cw3,cg3,cbb3,cw4,cg4,cbb4};
  for (int j=0;j<14;++j){ pc.s[j]=d_in[j+1]; pc.d[j]=pdst[j]; pc.sz[j]=psz[j]; }
  conv_params_kernel<<<117,256,0,stream>>>(pc, flag);

  prep_kernel<<<256,256,0,stream>>>(d_in[0], flag, cw_in, cb_in, xyz0, f0, stats);

  // ---- layer 1: 2048q/2048k, 16 -> 32
  knn_kernel<2048,64><<<dim3(32,32),256,0,stream>>>(xyz0, xyz0, 2048, knnb);
  edge_kernel<8,32,16><<<dim3(128,32),256,0,stream>>>(f0, nullptr, knnb, cw1, mmb, stats+0, 2048, 2048);
  fin_kernel<<<1024,256,0,stream>>>(mmb, stats+0, cg1, cbb1, f1, nullptr, flag, 0, 2048, 32, 1.f/262144.f, 2097152);

  // ---- FPS 2048 -> 512
  fps_kernel<2048,512><<<32,64,0,stream>>>(xyz0, idx1, xyz1);

  // ---- layer 2: 512q/2048k, 64 -> 64 (queries gathered via idx1)
  knn_kernel<2048,64><<<dim3(8,32),256,0,stream>>>(xyz1, xyz0, 512, knnb);
  edge_kernel<32,64,8><<<dim3(64,32),256,0,stream>>>(f1, idx1, knnb, cw2, mmb, stats+2048, 512, 2048);
  fin_kernel<<<1024,256,0,stream>>>(mmb, stats+2048, cg2, cbb2, f2, nullptr, flag, 0, 512, 64, 1.f/131072.f, 1048576);

  // ---- layer 3: 512q/512k, 128 -> 64
  knn_kernel<512,64><<<dim3(8,32),256,0,stream>>>(xyz1, xyz1, 512, knnb);
  edge_kernel<64,64,8><<<dim3(64,32),256,0,stream>>>(f2, nullptr, knnb, cw3, mmb, stats+4096, 512, 512);
  fin_kernel<<<1024,256,0,stream>>>(mmb, stats+4096, cg3, cbb3, f3, nullptr, flag, 0, 512, 64, 1.f/131072.f, 1048576);

  // ---- FPS 512 -> 128
  fps_kernel<512,128><<<32,64,0,stream>>>(xyz1, idx2, xyz2);

  // ---- layer 4: 128q/512k, 128 -> 128 (queries via idx2) -> final f output
  knn_kernel<512,64><<<dim3(2,32),256,0,stream>>>(xyz2, xyz1, 128, knnb);
  edge_kernel<64,128,4><<<dim3(32,32),256,0,stream>>>(f3, idx2, knnb, cw4, mmb, stats+6144, 128, 512);
  fin_kernel<<<1024,256,0,stream>>>(mmb, stats+6144, cg4, cbb4, nullptr, d_out, flag, 12288, 128, 128, 1.f/65536.f, 524288);

  // ---- coor output (B,3,128)
  coor_kernel<<<48,256,0,stream>>>(xyz2, d_out, flag);
}

// Round 7
// 1289.177 us; speedup vs baseline: 4.9032x; 1.0421x over previous
//
#include <hip/hip_runtime.h>
#include <hip/hip_bf16.h>

#define DEV __device__ __forceinline__

DEV float bf2f(unsigned short u){ return __uint_as_float(((unsigned)u)<<16); }
DEV unsigned short f2bf(float f){
  unsigned u = __float_as_uint(f);
  u += 0x7fffu + ((u>>16)&1u);   // RNE
  return (unsigned short)(u>>16);
}

// ---------------------------------------------------------------------------
// dtype detection: genuine bf16 N(0,1) data never has exponent >= 0xC0;
// fp32 read as ushorts has ~25% such halfwords. flag=1 -> inputs fp32.
__global__ __launch_bounds__(256) void detect_kernel(
    const unsigned short* __restrict__ x, int* __restrict__ flag){
  __shared__ int cnt;
  if (threadIdx.x==0) cnt = 0;
  __syncthreads();
  int local = 0;
  for (int i=threadIdx.x; i<4096; i+=256){
    int e = (x[i]>>7)&0xFF;
    if (e >= 0xC0) local++;
  }
  atomicAdd(&cnt, local);
  __syncthreads();
  if (threadIdx.x==0) *flag = (cnt > 64) ? 1 : 0;
}

// ---------------------------------------------------------------------------
struct PConv {
  const void* s[14];
  float*      d[14];
  int         sz[14];
};
__global__ __launch_bounds__(256) void conv_params_kernel(PConv p, const int* __restrict__ flag){
  bool isf = (*flag != 0);
  int i = blockIdx.x*256 + threadIdx.x;
  int seg = 0, off = i;
  #pragma unroll
  for (seg=0; seg<14; ++seg){
    if (off < p.sz[seg]) break;
    off -= p.sz[seg];
  }
  if (seg >= 14) return;
  float v = isf ? ((const float*)p.s[seg])[off]
                : bf2f(((const unsigned short*)p.s[seg])[off]);
  p.d[seg][off] = v;
}

// ---------------------------------------------------------------------------
// prep: coords (B,3,2048)->(B,2048,3) fp32, f0 = w_in@x + b_in, zero stats(8192).
__global__ __launch_bounds__(256) void prep_kernel(
    const void* __restrict__ xraw, const int* __restrict__ flag,
    const float* __restrict__ w_in, const float* __restrict__ b_in,
    float* __restrict__ xyz0, float* __restrict__ f0, float* __restrict__ stats){
  int i = blockIdx.x*256 + threadIdx.x;          // 32*2048 threads
  if (i < 8192) stats[i] = 0.f;
  bool isf = (*flag != 0);
  int b = i >> 11, n = i & 2047;
  size_t base = (size_t)b*3*2048 + n;
  float X, Y, Z;
  if (isf){
    const float* xf = (const float*)xraw;
    X = xf[base]; Y = xf[base+2048]; Z = xf[base+4096];
  } else {
    const unsigned short* xu = (const unsigned short*)xraw;
    X = bf2f(xu[base]); Y = bf2f(xu[base+2048]); Z = bf2f(xu[base+4096]);
  }
  float* o3 = xyz0 + (size_t)i*3;
  o3[0]=X; o3[1]=Y; o3[2]=Z;
  float* fo = f0 + (size_t)i*8;
  #pragma unroll
  for (int o=0;o<8;++o){
    fo[o] = w_in[o*3+0]*X + w_in[o*3+1]*Y + w_in[o*3+2]*Z + b_in[o];
  }
}

// ---------------------------------------------------------------------------
// Split-K kNN: 4 threads per query, thread h scans candidates m == h (mod 4)
// keeping a private sorted top-16 (strict-< insert => stable by index).
// Then a per-query leader 4-way merges the sorted lists by lex (d, idx) --
// exactly top_k's tie-by-lower-index semantics. kd LDS is reused for the
// merge lists (stride 65 floats per query kills the 64-way bank conflict).
template<int NK, int QB>
__global__ __launch_bounds__(QB*4, 4) void knn_kernel(
    const float* __restrict__ qxyz, const float* __restrict__ kxyz,
    int Nq, int* __restrict__ oidx){
  constexpr int BS = QB*4;
  constexpr int SM = (NK*4 > 130*QB) ? NK*4 : 130*QB;
  __shared__ __align__(16) float smem[SM];
  float4* kd = (float4*)smem;
  int b = blockIdx.y, t = threadIdx.x;
  for (int i=t; i<NK; i+=BS){
    const float* p = kxyz + ((size_t)b*NK + i)*3;
    float X=p[0], Y=p[1], Z=p[2];
    float sk = __fadd_rn(__fadd_rn(__fmul_rn(X,X),__fmul_rn(Y,Y)),__fmul_rn(Z,Z));
    kd[i] = make_float4(X,Y,Z,sk);
  }
  __syncthreads();
  int ql = t>>2, h = t&3;
  int q0 = blockIdx.x*QB;
  const float* qp = qxyz + ((size_t)b*Nq + q0 + ql)*3;
  float QX=qp[0], QY=qp[1], QZ=qp[2];
  float sq = __fadd_rn(__fadd_rn(__fmul_rn(QX,QX),__fmul_rn(QY,QY)),__fmul_rn(QZ,QZ));
  float dl[16]; int il[16];
  #pragma unroll
  for (int j=0;j<16;++j){ dl[j]=3.4e38f; il[j]=-1; }
  for (int i=0; i<NK/4; i+=8){
    float d[8];
    #pragma unroll
    for (int u=0;u<8;++u){
      float4 c = kd[4*(i+u)+h];
      float dot = __fadd_rn(__fadd_rn(__fmul_rn(QX,c.x),__fmul_rn(QY,c.y)),__fmul_rn(QZ,c.z));
      d[u] = __fsub_rn(__fadd_rn(sq, c.w), __fmul_rn(2.0f,dot));
    }
    float dmin = fminf(fminf(fminf(d[0],d[1]),fminf(d[2],d[3])),
                       fminf(fminf(d[4],d[5]),fminf(d[6],d[7])));
    if (dmin < dl[15]){
      #pragma unroll
      for (int u=0;u<8;++u){
        float du = d[u];
        if (du < dl[15]){               // strict <: equal dist keeps earlier index
          dl[15]=du; il[15]=4*(i+u)+h;
          #pragma unroll
          for (int s=15;s>0;--s){
            if (dl[s] < dl[s-1]){       // strict <: stable among equals
              float td=dl[s]; dl[s]=dl[s-1]; dl[s-1]=td;
              int   ti=il[s]; il[s]=il[s-1]; il[s-1]=ti;
            }
          }
        }
      }
    }
  }
  __syncthreads();                       // kd reads done; reuse smem for lists
  float* dbuf = smem;
  int*   ibuf = (int*)(smem + QB*65);
  int base = ql*65 + h*16;
  #pragma unroll
  for (int j=0;j<16;++j){ dbuf[base+j]=dl[j]; ibuf[base+j]=il[j]; }
  __syncthreads();
  if (t < QB){
    const float* db = dbuf + t*65;
    const int*   ib = ibuf + t*65;
    int p0=0,p1=0,p2=0,p3=0;
    int* op = oidx + ((size_t)b*Nq + q0 + t)*16;
    #pragma unroll 1
    for (int j=0;j<16;++j){
      float e0 = (p0<16)? db[p0]    : 3.5e38f; int i0 = (p0<16)? ib[p0]    : 0x7fffffff;
      float e1 = (p1<16)? db[16+p1] : 3.5e38f; int i1 = (p1<16)? ib[16+p1] : 0x7fffffff;
      float e2 = (p2<16)? db[32+p2] : 3.5e38f; int i2 = (p2<16)? ib[32+p2] : 0x7fffffff;
      float e3 = (p3<16)? db[48+p3] : 3.5e38f; int i3 = (p3<16)? ib[48+p3] : 0x7fffffff;
      float bd=e0; int bi=i0; int bh=0;
      if (e1<bd || (e1==bd && i1<bi)){ bd=e1; bi=i1; bh=1; }
      if (e2<bd || (e2==bd && i2<bi)){ bd=e2; bi=i2; bh=2; }
      if (e3<bd || (e3==bd && i3<bi)){ bd=e3; bi=i3; bh=3; }
      op[j]=bi;
      p0 += (bh==0); p1 += (bh==1); p2 += (bh==2); p3 += (bh==3);
    }
  }
}

// ---------------------------------------------------------------------------
// FPS: 4 waves, ONE barrier per step. Per-wave state is small (PPT=NP/256
// registers per array -> guaranteed resident; round-6's VGPR=92 < needed-128
// showed the single-wave PPT=32 version was spilling/re-loading each step).
// Wave-local XOR-butterfly argmax with lex (val desc, idx asc) == ref ties;
// 4 wave-candidates merge via parity double-buffered LDS slots. Global
// stores for step g-1 issue at the top of step g right after the broadcast
// centroid read, so they drain during the scan (never block the barrier).
// Exact fp32 no-FMA arithmetic throughout.
template<int NP,int G>
__global__ __launch_bounds__(256,1) void fps_kernel(
    const float* __restrict__ xyz, int* __restrict__ oidx, float* __restrict__ oxyz){
  constexpr int PPT = NP/256;
  __shared__ __align__(16) float4 xl4[NP];
  __shared__ float2 cand[2][4];
  int b = blockIdx.x, t = threadIdx.x;
  int w = t>>6;
  float px[PPT], py[PPT], pz[PPT], dist[PPT];
  #pragma unroll
  for (int j=0;j<PPT;++j){
    int gi = t + j*256;
    const float* p = xyz + ((size_t)b*NP + gi)*3;
    float X=p[0], Y=p[1], Z=p[2];
    px[j]=X; py[j]=Y; pz[j]=Z; dist[j]=1e10f;
    xl4[gi] = make_float4(X,Y,Z,0.f);
  }
  __syncthreads();
  int Bi = 0;
  for (int g=1; g<G; ++g){
    float4 c = xl4[Bi];                  // broadcast read (uniform address)
    if (t==0){                           // store step g-1 results; drains in scan
      oidx[(size_t)b*G + (g-1)] = Bi;
      float* op = oxyz + ((size_t)b*G + (g-1))*3;
      op[0]=c.x; op[1]=c.y; op[2]=c.z;
    }
    float bv = -1.f; int bi = 0x7fffffff;
    #pragma unroll
    for (int j=0;j<PPT;++j){
      float dx=__fsub_rn(px[j],c.x), dy=__fsub_rn(py[j],c.y), dz=__fsub_rn(pz[j],c.z);
      float d = __fadd_rn(__fadd_rn(__fmul_rn(dx,dx),__fmul_rn(dy,dy)),__fmul_rn(dz,dz));
      float nd = fminf(dist[j], d);
      dist[j] = nd;
      bool cc = (nd > bv);               // ascending idx in-lane: first-max kept
      bv = cc ? nd : bv;
      bi = cc ? (t + j*256) : bi;
    }
    #pragma unroll
    for (int off=1; off<64; off<<=1){
      float ov = __shfl_xor(bv, off);
      int   oi = __shfl_xor(bi, off);
      bool cc = (ov > bv) || (ov == bv && oi < bi);
      bv = cc ? ov : bv;
      bi = cc ? oi : bi;
    }
    int par = g & 1;
    if ((t&63)==0) cand[par][w] = make_float2(bv, __int_as_float(bi));
    __syncthreads();
    float2 c0=cand[par][0], c1=cand[par][1], c2=cand[par][2], c3=cand[par][3];
    float Bv=c0.x; Bi=__float_as_int(c0.y);
    int i1=__float_as_int(c1.y); if (c1.x>Bv || (c1.x==Bv && i1<Bi)){ Bv=c1.x; Bi=i1; }
    int i2=__float_as_int(c2.y); if (c2.x>Bv || (c2.x==Bv && i2<Bi)){ Bv=c2.x; Bi=i2; }
    int i3=__float_as_int(c3.y); if (c3.x>Bv || (c3.x==Bv && i3<Bi)){ Bv=c3.x; Bi=i3; }
  }
  if (t==0){                             // final winner
    oidx[(size_t)b*G + (G-1)] = Bi;
    float4 c = xl4[Bi];
    float* op = oxyz + ((size_t)b*G + (G-1))*3;
    op[0]=c.x; op[1]=c.y; op[2]=c.z;
  }
}

// ---------------------------------------------------------------------------
// EdgeConv pre-norm, query-batched. Block: QB queries, 256 threads, thread owns
// (ql, o, o+COUT/2) and ALL 16 k's. Key identity: the xq half of the edge
// feature is k-invariant, so y[o,k] = sum_{c<CF} w1[o,c]*nbr[c,k] + z[o],
// z = sum_c (w2[o,c]-w1[o,c])*fq[c]. Weights staged per CF-half (LDS <= 52KB).
// Stats: thread -> LDS atomic (8 floats) -> 8-way bucketed global atomics.
template<int CF,int COUT,int QB>
__global__ __launch_bounds__(256) void edge_kernel(
    const float* __restrict__ fk, const int* __restrict__ sel,
    const int* __restrict__ knn, const float* __restrict__ w,
    float* __restrict__ mm, float* __restrict__ stats, int Nq, int Nk){
  constexpr int CIN = 2*CF;
  constexpr int GPQ = COUT/2;        // threads per query (2 outputs/thread)
  constexpr int WS  = COUT+1;        // padded weight stride (conflict-free stage)
  constexpr int ESTR= CF*16+8;       // per-query e stride (+8 staggers banks)
  static_assert(QB*GPQ == 256, "block mapping");
  __shared__ float wtb[CF*WS];
  __shared__ __align__(16) float e[QB*ESTR];
  __shared__ float fqs[QB*CF];
  __shared__ float sS[8];            // [0..3]=sum per group, [4..7]=sumsq
  int b = blockIdx.y, t = threadIdx.x;
  int q0 = blockIdx.x*QB;

  if (t<8) sS[t]=0.f;
  for (int i=t; i<QB*CF; i+=256){
    int ql = i/CF, c = i&(CF-1);
    int qi = sel ? sel[b*Nq + q0 + ql] : (q0 + ql);
    fqs[i] = fk[((size_t)b*Nk + qi)*CF + c];
  }
  for (int i=t; i<CF*COUT; i+=256){
    int o = i/CF, c = i&(CF-1);
    wtb[c*WS+o] = w[o*CIN + c];
  }
  if (t < QB*16){
    int ql = t>>4, k = t&15;
    int nid = knn[((size_t)b*Nq + q0 + ql)*16 + k];
    const float4* row = (const float4*)(fk + ((size_t)b*Nk + nid)*CF);
    float* ep = e + ql*ESTR + k;
    #pragma unroll
    for (int c4=0; c4<CF/4; ++c4){
      float4 v = row[c4];
      ep[(c4*4+0)*16]=v.x; ep[(c4*4+1)*16]=v.y; ep[(c4*4+2)*16]=v.z; ep[(c4*4+3)*16]=v.w;
    }
  }
  __syncthreads();

  int ql = t/GPQ, o = t%GPQ;
  const float* eb = e + ql*ESTR;
  const float* fqb = fqs + ql*CF;
  float y0[16], y1[16];
  #pragma unroll
  for (int k=0;k<16;++k){ y0[k]=0.f; y1[k]=0.f; }
  float zA0=0.f, zA1=0.f;
  for (int c=0;c<CF;++c){
    float w0 = wtb[c*WS+o];
    float w1 = wtb[c*WS+o+GPQ];
    float fqc = fqb[c];
    zA0 = fmaf(w0,fqc,zA0); zA1 = fmaf(w1,fqc,zA1);
    const float4* ev4 = (const float4*)(eb + c*16);
    #pragma unroll
    for (int k4=0;k4<4;++k4){
      float4 ev = ev4[k4];
      y0[k4*4+0]=fmaf(w0,ev.x,y0[k4*4+0]); y0[k4*4+1]=fmaf(w0,ev.y,y0[k4*4+1]);
      y0[k4*4+2]=fmaf(w0,ev.z,y0[k4*4+2]); y0[k4*4+3]=fmaf(w0,ev.w,y0[k4*4+3]);
      y1[k4*4+0]=fmaf(w1,ev.x,y1[k4*4+0]); y1[k4*4+1]=fmaf(w1,ev.y,y1[k4*4+1]);
      y1[k4*4+2]=fmaf(w1,ev.z,y1[k4*4+2]); y1[k4*4+3]=fmaf(w1,ev.w,y1[k4*4+3]);
    }
  }
  __syncthreads();
  for (int i=t; i<CF*COUT; i+=256){
    int oo = i/CF, c = i&(CF-1);
    wtb[c*WS+oo] = w[oo*CIN + CF + c];
  }
  __syncthreads();
  float zB0=0.f, zB1=0.f;
  for (int c=0;c<CF;++c){
    float fqc = fqb[c];
    zB0 = fmaf(wtb[c*WS+o],fqc,zB0);
    zB1 = fmaf(wtb[c*WS+o+GPQ],fqc,zB1);
  }
  float z0 = zB0 - zA0, z1 = zB1 - zA1;

  float mx0=-3.4e38f, mn0=3.4e38f, s0=0.f, q0s=0.f;
  float mx1=-3.4e38f, mn1=3.4e38f, s1=0.f, q1s=0.f;
  #pragma unroll
  for (int k=0;k<16;++k){
    float v0 = y0[k]+z0, v1 = y1[k]+z1;
    mx0=fmaxf(mx0,v0); mn0=fminf(mn0,v0); s0+=v0; q0s=fmaf(v0,v0,q0s);
    mx1=fmaxf(mx1,v1); mn1=fminf(mn1,v1); s1+=v1; q1s=fmaf(v1,v1,q1s);
  }
  int g0 = o/(COUT/4);               // in {0,1}; second output is g0+2
  atomicAdd(&sS[g0],   s0); atomicAdd(&sS[4+g0],   q0s);
  atomicAdd(&sS[g0+2], s1); atomicAdd(&sS[6+g0],   q1s);
  size_t mi0 = ((size_t)b*Nq + q0 + ql)*COUT + o;
  ((float2*)mm)[mi0]       = make_float2(mx0,mn0);
  ((float2*)mm)[mi0+GPQ]   = make_float2(mx1,mn1);
  __syncthreads();
  if (t<8){
    int g = t>>1, which = t&1;
    float val = which ? sS[4+g] : sS[g];
    atomicAdd(&stats[(((size_t)b*4+g)*8 + (blockIdx.x&7))*2 + which], val);
  }
}

// ---------------------------------------------------------------------------
// finalize: sum stat buckets, GN affine on max (min if a<0) + LeakyReLU.
__global__ __launch_bounds__(256) void fin_kernel(
    const float* __restrict__ mm, const float* __restrict__ stats,
    const float* __restrict__ gam, const float* __restrict__ bet,
    float* __restrict__ fo, void* __restrict__ outbase, const int* __restrict__ flag,
    int outoff, int Nq, int COUT, float invcnt, int total){
  for (int i = blockIdx.x*256 + threadIdx.x; i<total; i += gridDim.x*256){
    int o = i % COUT;
    int r = i / COUT;
    int q = r % Nq;
    int b = r / Nq;
    int g = o / (COUT>>2);
    const float* sp = stats + ((size_t)(b*4+g))*16;
    float s=0.f, s2=0.f;
    #pragma unroll
    for (int nb=0;nb<8;++nb){ s += sp[nb*2]; s2 += sp[nb*2+1]; }
    float mean = s*invcnt;
    float var  = fmaxf(s2*invcnt - mean*mean, 0.f);
    float inv  = 1.0f / sqrtf(var + 1e-5f);
    float a  = gam[o] * inv;
    float bb = bet[o] - a*mean;
    const float* mp = mm + (size_t)i*2;
    float xv = (a>=0.f) ? mp[0] : mp[1];  // monotone affine: max commutes
    float v = fmaf(a, xv, bb);
    v = (v>=0.f) ? v : 0.2f*v;
    if (fo) fo[i]=v;
    if (outbase){
      int idx = outoff + ((b*COUT + o)*Nq + q);
      if (*flag) ((float*)outbase)[idx] = v;
      else       ((unsigned short*)outbase)[idx] = f2bf(v);
    }
  }
}

__global__ __launch_bounds__(256) void coor_kernel(
    const float* __restrict__ xyz2, void* __restrict__ outbase,
    const int* __restrict__ flag){
  int i = blockIdx.x*256+threadIdx.x;   // 32*3*128
  int m = i & 127;
  int c = (i>>7) % 3;
  int b = i / 384;
  float v = xyz2[((size_t)b*128+m)*3 + c];
  if (*flag) ((float*)outbase)[i] = v;
  else       ((unsigned short*)outbase)[i] = f2bf(v);
}

// ---------------------------------------------------------------------------
extern "C" void kernel_launch(void* const* d_in, const int* in_sizes, int n_in,
                              void* d_out, int out_size, void* d_ws, size_t ws_size,
                              hipStream_t stream){
  float* W    = (float*)d_ws;
  float* xyz0 = W;                      // 196608
  float* f0   = W + 196608;             // 524288
  float* f1   = W + 720896;             // 2097152
  float* xyz1 = W + 2818048;            // 49152
  float* f2   = W + 2867200;            // 1048576
  float* f3   = W + 3915776;            // 1048576
  float* xyz2 = W + 4964352;            // 12288
  float* stats= W + 4976640;            // 8192 (4 layers x 32 x 4 x 8buckets x 2)
  int*   flag = (int*)(W + 4984832);    // 16 (pad)
  float* PRM  = W + 4984848;            // 29792 canonical fp32 params
  int*  idx1  = (int*)(W + 5014640);    // 16384
  int*  idx2  = (int*)(W + 5031024);    // 4096
  float* SCR  = W + 5035120;            // aliased per-layer scratch
  int*   knnb = (int*)SCR;              // <= 1048576 ints
  float* mmb  = SCR + 1048576;          // <= 4194304 floats
  // total ~ 41.1 MB

  float* cw_in = PRM;          // 24
  float* cb_in = PRM+24;       // 8
  float* cw1 = PRM+32;   float* cg1 = PRM+544;   float* cbb1 = PRM+576;   // 512,32,32
  float* cw2 = PRM+608;  float* cg2 = PRM+4704;  float* cbb2 = PRM+4768;  // 4096,64,64
  float* cw3 = PRM+4832; float* cg3 = PRM+13024; float* cbb3 = PRM+13088; // 8192,64,64
  float* cw4 = PRM+13152;float* cg4 = PRM+29536; float* cbb4 = PRM+29664; // 16384,128,128

  detect_kernel<<<1,256,0,stream>>>((const unsigned short*)d_in[0], flag);

  PConv pc;
  const int psz[14] = {24,8,512,32,32,4096,64,64,8192,64,64,16384,128,128};
  float* pdst[14] = {cw_in,cb_in,cw1,cg1,cbb1,cw2,cg2,cbb2,cw3,cg3,cbb3,cw4,cg4,cbb4};
  for (int j=0;j<14;++j){ pc.s[j]=d_in[j+1]; pc.d[j]=pdst[j]; pc.sz[j]=psz[j]; }
  conv_params_kernel<<<117,256,0,stream>>>(pc, flag);

  prep_kernel<<<256,256,0,stream>>>(d_in[0], flag, cw_in, cb_in, xyz0, f0, stats);

  // ---- layer 1: 2048q/2048k, 16 -> 32
  knn_kernel<2048,64><<<dim3(32,32),256,0,stream>>>(xyz0, xyz0, 2048, knnb);
  edge_kernel<8,32,16><<<dim3(128,32),256,0,stream>>>(f0, nullptr, knnb, cw1, mmb, stats+0, 2048, 2048);
  fin_kernel<<<1024,256,0,stream>>>(mmb, stats+0, cg1, cbb1, f1, nullptr, flag, 0, 2048, 32, 1.f/262144.f, 2097152);

  // ---- FPS 2048 -> 512
  fps_kernel<2048,512><<<32,256,0,stream>>>(xyz0, idx1, xyz1);

  // ---- layer 2: 512q/2048k, 64 -> 64 (queries gathered via idx1)
  knn_kernel<2048,64><<<dim3(8,32),256,0,stream>>>(xyz1, xyz0, 512, knnb);
  edge_kernel<32,64,8><<<dim3(64,32),256,0,stream>>>(f1, idx1, knnb, cw2, mmb, stats+2048, 512, 2048);
  fin_kernel<<<1024,256,0,stream>>>(mmb, stats+2048, cg2, cbb2, f2, nullptr, flag, 0, 512, 64, 1.f/131072.f, 1048576);

  // ---- layer 3: 512q/512k, 128 -> 64
  knn_kernel<512,64><<<dim3(8,32),256,0,stream>>>(xyz1, xyz1, 512, knnb);
  edge_kernel<64,64,8><<<dim3(64,32),256,0,stream>>>(f2, nullptr, knnb, cw3, mmb, stats+4096, 512, 512);
  fin_kernel<<<1024,256,0,stream>>>(mmb, stats+4096, cg3, cbb3, f3, nullptr, flag, 0, 512, 64, 1.f/131072.f, 1048576);

  // ---- FPS 512 -> 128
  fps_kernel<512,128><<<32,256,0,stream>>>(xyz1, idx2, xyz2);

  // ---- layer 4: 128q/512k, 128 -> 128 (queries via idx2) -> final f output
  knn_kernel<512,64><<<dim3(2,32),256,0,stream>>>(xyz2, xyz1, 128, knnb);
  edge_kernel<64,128,4><<<dim3(32,32),256,0,stream>>>(f3, idx2, knnb, cw4, mmb, stats+6144, 128, 512);
  fin_kernel<<<1024,256,0,stream>>>(mmb, stats+6144, cg4, cbb4, nullptr, d_out, flag, 12288, 128, 128, 1.f/65536.f, 524288);

  // ---- coor output (B,3,128)
  coor_kernel<<<48,256,0,stream>>>(xyz2, d_out, flag);
}

// Round 8
// 837.205 us; speedup vs baseline: 7.5502x; 1.5399x over previous
//
#include <hip/hip_runtime.h>
#include <hip/hip_bf16.h>

#define DEV __device__ __forceinline__

DEV float bf2f(unsigned short u){ return __uint_as_float(((unsigned)u)<<16); }
DEV unsigned short f2bf(float f){
  unsigned u = __float_as_uint(f);
  u += 0x7fffu + ((u>>16)&1u);   // RNE
  return (unsigned short)(u>>16);
}

// ---------------------------------------------------------------------------
// dtype detection: genuine bf16 N(0,1) data never has exponent >= 0xC0;
// fp32 read as ushorts has ~25% such halfwords. flag=1 -> inputs fp32.
__global__ __launch_bounds__(256) void detect_kernel(
    const unsigned short* __restrict__ x, int* __restrict__ flag){
  __shared__ int cnt;
  if (threadIdx.x==0) cnt = 0;
  __syncthreads();
  int local = 0;
  for (int i=threadIdx.x; i<4096; i+=256){
    int e = (x[i]>>7)&0xFF;
    if (e >= 0xC0) local++;
  }
  atomicAdd(&cnt, local);
  __syncthreads();
  if (threadIdx.x==0) *flag = (cnt > 64) ? 1 : 0;
}

// ---------------------------------------------------------------------------
struct PConv {
  const void* s[14];
  float*      d[14];
  int         sz[14];
};
__global__ __launch_bounds__(256) void conv_params_kernel(PConv p, const int* __restrict__ flag){
  bool isf = (*flag != 0);
  int i = blockIdx.x*256 + threadIdx.x;
  int seg = 0, off = i;
  #pragma unroll
  for (seg=0; seg<14; ++seg){
    if (off < p.sz[seg]) break;
    off -= p.sz[seg];
  }
  if (seg >= 14) return;
  float v = isf ? ((const float*)p.s[seg])[off]
                : bf2f(((const unsigned short*)p.s[seg])[off]);
  p.d[seg][off] = v;
}

// ---------------------------------------------------------------------------
// prep: coords (B,3,2048)->(B,2048,3) fp32, f0 = w_in@x + b_in, zero stats(8192).
__global__ __launch_bounds__(256) void prep_kernel(
    const void* __restrict__ xraw, const int* __restrict__ flag,
    const float* __restrict__ w_in, const float* __restrict__ b_in,
    float* __restrict__ xyz0, float* __restrict__ f0, float* __restrict__ stats){
  int i = blockIdx.x*256 + threadIdx.x;          // 32*2048 threads
  if (i < 8192) stats[i] = 0.f;
  bool isf = (*flag != 0);
  int b = i >> 11, n = i & 2047;
  size_t base = (size_t)b*3*2048 + n;
  float X, Y, Z;
  if (isf){
    const float* xf = (const float*)xraw;
    X = xf[base]; Y = xf[base+2048]; Z = xf[base+4096];
  } else {
    const unsigned short* xu = (const unsigned short*)xraw;
    X = bf2f(xu[base]); Y = bf2f(xu[base+2048]); Z = bf2f(xu[base+4096]);
  }
  float* o3 = xyz0 + (size_t)i*3;
  o3[0]=X; o3[1]=Y; o3[2]=Z;
  float* fo = f0 + (size_t)i*8;
  #pragma unroll
  for (int o=0;o<8;++o){
    fo[o] = w_in[o*3+0]*X + w_in[o*3+1]*Y + w_in[o*3+2]*Z + b_in[o];
  }
}

// ---------------------------------------------------------------------------
// Split-K kNN body (256 threads): 4 threads/query, thread h scans m==h (mod 4),
// private sorted top-16 (strict-< insert => stable), leader 4-way lex merge.
// smem: >= max(NK*4, 130*QB) floats.
template<int NK, int QB>
DEV void knn_body(float* smem, const float* __restrict__ qxyz,
                  const float* __restrict__ kxyz, int Nq,
                  int* __restrict__ oidx, int bx, int b){
  float4* kd = (float4*)smem;
  int t = threadIdx.x;
  for (int i=t; i<NK; i+=256){
    const float* p = kxyz + ((size_t)b*NK + i)*3;
    float X=p[0], Y=p[1], Z=p[2];
    float sk = __fadd_rn(__fadd_rn(__fmul_rn(X,X),__fmul_rn(Y,Y)),__fmul_rn(Z,Z));
    kd[i] = make_float4(X,Y,Z,sk);
  }
  __syncthreads();
  int ql = t>>2, h = t&3;
  int q0 = bx*QB;
  const float* qp = qxyz + ((size_t)b*Nq + q0 + ql)*3;
  float QX=qp[0], QY=qp[1], QZ=qp[2];
  float sq = __fadd_rn(__fadd_rn(__fmul_rn(QX,QX),__fmul_rn(QY,QY)),__fmul_rn(QZ,QZ));
  float dl[16]; int il[16];
  #pragma unroll
  for (int j=0;j<16;++j){ dl[j]=3.4e38f; il[j]=-1; }
  for (int i=0; i<NK/4; i+=8){
    float d[8];
    #pragma unroll
    for (int u=0;u<8;++u){
      float4 c = kd[4*(i+u)+h];
      float dot = __fadd_rn(__fadd_rn(__fmul_rn(QX,c.x),__fmul_rn(QY,c.y)),__fmul_rn(QZ,c.z));
      d[u] = __fsub_rn(__fadd_rn(sq, c.w), __fmul_rn(2.0f,dot));
    }
    float dmin = fminf(fminf(fminf(d[0],d[1]),fminf(d[2],d[3])),
                       fminf(fminf(d[4],d[5]),fminf(d[6],d[7])));
    if (dmin < dl[15]){
      #pragma unroll
      for (int u=0;u<8;++u){
        float du = d[u];
        if (du < dl[15]){               // strict <: equal dist keeps earlier index
          dl[15]=du; il[15]=4*(i+u)+h;
          #pragma unroll
          for (int s=15;s>0;--s){
            if (dl[s] < dl[s-1]){       // strict <: stable among equals
              float td=dl[s]; dl[s]=dl[s-1]; dl[s-1]=td;
              int   ti=il[s]; il[s]=il[s-1]; il[s-1]=ti;
            }
          }
        }
      }
    }
  }
  __syncthreads();                       // kd reads done; reuse smem for lists
  float* dbuf = smem;
  int*   ibuf = (int*)(smem + QB*65);
  int base = ql*65 + h*16;
  #pragma unroll
  for (int j=0;j<16;++j){ dbuf[base+j]=dl[j]; ibuf[base+j]=il[j]; }
  __syncthreads();
  if (t < QB){
    const float* db = dbuf + t*65;
    const int*   ib = ibuf + t*65;
    int p0=0,p1=0,p2=0,p3=0;
    int* op = oidx + ((size_t)b*Nq + q0 + t)*16;
    #pragma unroll 1
    for (int j=0;j<16;++j){
      float e0 = (p0<16)? db[p0]    : 3.5e38f; int i0 = (p0<16)? ib[p0]    : 0x7fffffff;
      float e1 = (p1<16)? db[16+p1] : 3.5e38f; int i1 = (p1<16)? ib[16+p1] : 0x7fffffff;
      float e2 = (p2<16)? db[32+p2] : 3.5e38f; int i2 = (p2<16)? ib[32+p2] : 0x7fffffff;
      float e3 = (p3<16)? db[48+p3] : 3.5e38f; int i3 = (p3<16)? ib[48+p3] : 0x7fffffff;
      float bd=e0; int bi=i0; int bh=0;
      if (e1<bd || (e1==bd && i1<bi)){ bd=e1; bi=i1; bh=1; }
      if (e2<bd || (e2==bd && i2<bi)){ bd=e2; bi=i2; bh=2; }
      if (e3<bd || (e3==bd && i3<bi)){ bd=e3; bi=i3; bh=3; }
      op[j]=bi;
      p0 += (bh==0); p1 += (bh==1); p2 += (bh==2); p3 += (bh==3);
    }
  }
  __syncthreads();                       // safe smem handoff (fused callers)
}

// ---------------------------------------------------------------------------
// FPS body (256 threads, 4 waves, one barrier/step). Packed 64-bit argmax key
// (fbits(dist)<<32)|(~idx): dist>=0 so float bits are monotone; umax == lex
// (dist desc, idx asc) == ref argmax tie-break. No in-loop global stores:
// winners accumulate in LDS, oidx/oxyz written in parallel at the end.
// smem: NP*4 + 16 + G floats. Exact fp32 no-FMA math.
template<int NP,int G>
DEV void fps_body(float* smem, const float* __restrict__ xyz,
                  int* __restrict__ oidx, float* __restrict__ oxyz, int b){
  constexpr int PPT = NP/256;
  float4* xl4 = (float4*)smem;
  unsigned long long* candK = (unsigned long long*)(smem + NP*4);  // 2par x 4waves
  int* selidx = (int*)(smem + NP*4 + 16);
  int t = threadIdx.x, w = t>>6;
  float px[PPT], py[PPT], pz[PPT], dist[PPT];
  #pragma unroll
  for (int j=0;j<PPT;++j){
    int gi = t + j*256;
    const float* p = xyz + ((size_t)b*NP + gi)*3;
    float X=p[0], Y=p[1], Z=p[2];
    px[j]=X; py[j]=Y; pz[j]=Z; dist[j]=1e10f;
    xl4[gi] = make_float4(X,Y,Z,0.f);
  }
  if (t==0) selidx[0] = 0;
  __syncthreads();
  int Bi = 0;
  for (int g=1; g<G; ++g){
    float4 c = xl4[Bi];                  // uniform broadcast read
    float bv = -1.f; int bi = 0x7fffffff;
    #pragma unroll
    for (int j=0;j<PPT;++j){
      float dx=__fsub_rn(px[j],c.x), dy=__fsub_rn(py[j],c.y), dz=__fsub_rn(pz[j],c.z);
      float d = __fadd_rn(__fadd_rn(__fmul_rn(dx,dx),__fmul_rn(dy,dy)),__fmul_rn(dz,dz));
      float nd = fminf(dist[j], d);
      dist[j] = nd;
      bool cc = (nd > bv);               // ascending idx in-lane: first-max kept
      bv = cc ? nd : bv;
      bi = cc ? (t + j*256) : bi;
    }
    unsigned long long key =
        ((unsigned long long)__float_as_uint(bv) << 32) | (unsigned)(0xFFFFFFFFu - bi);
    #pragma unroll
    for (int off=1; off<64; off<<=1){
      unsigned long long ok = __shfl_xor(key, off);
      key = (ok > key) ? ok : key;
    }
    int par = g & 1;
    if ((t&63)==0) candK[par*4 + w] = key;
    __syncthreads();
    unsigned long long k0=candK[par*4+0], k1=candK[par*4+1],
                       k2=candK[par*4+2], k3=candK[par*4+3];
    unsigned long long kk = k0 > k1 ? k0 : k1;
    unsigned long long kl = k2 > k3 ? k2 : k3;
    kk = kk > kl ? kk : kl;
    Bi = (int)(0xFFFFFFFFu - (unsigned)kk);
    if (t==0) selidx[g] = Bi;
  }
  __syncthreads();
  for (int i=t; i<G; i+=256){
    int s = selidx[i];
    float4 c = xl4[s];
    oidx[(size_t)b*G + i] = s;
    float* op = oxyz + ((size_t)b*G + i)*3;
    op[0]=c.x; op[1]=c.y; op[2]=c.z;
  }
}

// ---------------------------------------------------------------------------
// Fused launches: FPS blocks first (grab CU slots immediately), knn fills the
// rest of the machine. Events are banned, so this is the only overlap path.
__global__ __launch_bounds__(256,4) void fused1_kernel(
    const float* __restrict__ xyz0, int* __restrict__ knnb1,
    int* __restrict__ idx1, float* __restrict__ xyz1){
  __shared__ __align__(16) float smem[8720];   // max(fps1 8720, knn 8320) floats
  int bx = blockIdx.x;
  if (bx < 32){
    fps_body<2048,512>(smem, xyz0, idx1, xyz1, bx);
  } else {
    int rid = bx - 32;                          // 1024 knn1 blocks
    knn_body<2048,64>(smem, xyz0, xyz0, 2048, knnb1, rid & 31, rid >> 5);
  }
}

__global__ __launch_bounds__(256,4) void fused2_kernel(
    const float* __restrict__ xyz0, const float* __restrict__ xyz1,
    int* __restrict__ knnb2, int* __restrict__ knnb3,
    int* __restrict__ idx2, float* __restrict__ xyz2){
  __shared__ __align__(16) float smem[8320];
  int bx = blockIdx.x;
  if (bx < 32){
    fps_body<512,128>(smem, xyz1, idx2, xyz2, bx);
  } else if (bx < 288){
    int rid = bx - 32;                          // 256 knn2 blocks
    knn_body<2048,64>(smem, xyz1, xyz0, 512, knnb2, rid & 7, rid >> 3);
  } else {
    int rid = bx - 288;                         // 256 knn3 blocks
    knn_body<512,64>(smem, xyz1, xyz1, 512, knnb3, rid & 7, rid >> 3);
  }
}

template<int NK,int QB>
__global__ __launch_bounds__(QB*4,4) void knn_kernel(
    const float* __restrict__ qxyz, const float* __restrict__ kxyz,
    int Nq, int* __restrict__ oidx){
  constexpr int SM = (NK*4 > 130*QB) ? NK*4 : 130*QB;
  __shared__ __align__(16) float smem[SM];
  knn_body<NK,QB>(smem, qxyz, kxyz, Nq, oidx, blockIdx.x, blockIdx.y);
}

// ---------------------------------------------------------------------------
// EdgeConv pre-norm, query-batched (see round-3 notes; unchanged).
template<int CF,int COUT,int QB>
__global__ __launch_bounds__(256) void edge_kernel(
    const float* __restrict__ fk, const int* __restrict__ sel,
    const int* __restrict__ knn, const float* __restrict__ w,
    float* __restrict__ mm, float* __restrict__ stats, int Nq, int Nk){
  constexpr int CIN = 2*CF;
  constexpr int GPQ = COUT/2;
  constexpr int WS  = COUT+1;
  constexpr int ESTR= CF*16+8;
  static_assert(QB*GPQ == 256, "block mapping");
  __shared__ float wtb[CF*WS];
  __shared__ __align__(16) float e[QB*ESTR];
  __shared__ float fqs[QB*CF];
  __shared__ float sS[8];
  int b = blockIdx.y, t = threadIdx.x;
  int q0 = blockIdx.x*QB;

  if (t<8) sS[t]=0.f;
  for (int i=t; i<QB*CF; i+=256){
    int ql = i/CF, c = i&(CF-1);
    int qi = sel ? sel[b*Nq + q0 + ql] : (q0 + ql);
    fqs[i] = fk[((size_t)b*Nk + qi)*CF + c];
  }
  for (int i=t; i<CF*COUT; i+=256){
    int o = i/CF, c = i&(CF-1);
    wtb[c*WS+o] = w[o*CIN + c];
  }
  if (t < QB*16){
    int ql = t>>4, k = t&15;
    int nid = knn[((size_t)b*Nq + q0 + ql)*16 + k];
    const float4* row = (const float4*)(fk + ((size_t)b*Nk + nid)*CF);
    float* ep = e + ql*ESTR + k;
    #pragma unroll
    for (int c4=0; c4<CF/4; ++c4){
      float4 v = row[c4];
      ep[(c4*4+0)*16]=v.x; ep[(c4*4+1)*16]=v.y; ep[(c4*4+2)*16]=v.z; ep[(c4*4+3)*16]=v.w;
    }
  }
  __syncthreads();

  int ql = t/GPQ, o = t%GPQ;
  const float* eb = e + ql*ESTR;
  const float* fqb = fqs + ql*CF;
  float y0[16], y1[16];
  #pragma unroll
  for (int k=0;k<16;++k){ y0[k]=0.f; y1[k]=0.f; }
  float zA0=0.f, zA1=0.f;
  for (int c=0;c<CF;++c){
    float w0 = wtb[c*WS+o];
    float w1 = wtb[c*WS+o+GPQ];
    float fqc = fqb[c];
    zA0 = fmaf(w0,fqc,zA0); zA1 = fmaf(w1,fqc,zA1);
    const float4* ev4 = (const float4*)(eb + c*16);
    #pragma unroll
    for (int k4=0;k4<4;++k4){
      float4 ev = ev4[k4];
      y0[k4*4+0]=fmaf(w0,ev.x,y0[k4*4+0]); y0[k4*4+1]=fmaf(w0,ev.y,y0[k4*4+1]);
      y0[k4*4+2]=fmaf(w0,ev.z,y0[k4*4+2]); y0[k4*4+3]=fmaf(w0,ev.w,y0[k4*4+3]);
      y1[k4*4+0]=fmaf(w1,ev.x,y1[k4*4+0]); y1[k4*4+1]=fmaf(w1,ev.y,y1[k4*4+1]);
      y1[k4*4+2]=fmaf(w1,ev.z,y1[k4*4+2]); y1[k4*4+3]=fmaf(w1,ev.w,y1[k4*4+3]);
    }
  }
  __syncthreads();
  for (int i=t; i<CF*COUT; i+=256){
    int oo = i/CF, c = i&(CF-1);
    wtb[c*WS+oo] = w[oo*CIN + CF + c];
  }
  __syncthreads();
  float zB0=0.f, zB1=0.f;
  for (int c=0;c<CF;++c){
    float fqc = fqb[c];
    zB0 = fmaf(wtb[c*WS+o],fqc,zB0);
    zB1 = fmaf(wtb[c*WS+o+GPQ],fqc,zB1);
  }
  float z0 = zB0 - zA0, z1 = zB1 - zA1;

  float mx0=-3.4e38f, mn0=3.4e38f, s0=0.f, q0s=0.f;
  float mx1=-3.4e38f, mn1=3.4e38f, s1=0.f, q1s=0.f;
  #pragma unroll
  for (int k=0;k<16;++k){
    float v0 = y0[k]+z0, v1 = y1[k]+z1;
    mx0=fmaxf(mx0,v0); mn0=fminf(mn0,v0); s0+=v0; q0s=fmaf(v0,v0,q0s);
    mx1=fmaxf(mx1,v1); mn1=fminf(mn1,v1); s1+=v1; q1s=fmaf(v1,v1,q1s);
  }
  int g0 = o/(COUT/4);
  atomicAdd(&sS[g0],   s0); atomicAdd(&sS[4+g0],   q0s);
  atomicAdd(&sS[g0+2], s1); atomicAdd(&sS[6+g0],   q1s);
  size_t mi0 = ((size_t)b*Nq + q0 + ql)*COUT + o;
  ((float2*)mm)[mi0]       = make_float2(mx0,mn0);
  ((float2*)mm)[mi0+GPQ]   = make_float2(mx1,mn1);
  __syncthreads();
  if (t<8){
    int g = t>>1, which = t&1;
    float val = which ? sS[4+g] : sS[g];
    atomicAdd(&stats[(((size_t)b*4+g)*8 + (blockIdx.x&7))*2 + which], val);
  }
}

// ---------------------------------------------------------------------------
// finalize: sum stat buckets, GN affine on max (min if a<0) + LeakyReLU.
__global__ __launch_bounds__(256) void fin_kernel(
    const float* __restrict__ mm, const float* __restrict__ stats,
    const float* __restrict__ gam, const float* __restrict__ bet,
    float* __restrict__ fo, void* __restrict__ outbase, const int* __restrict__ flag,
    int outoff, int Nq, int COUT, float invcnt, int total){
  for (int i = blockIdx.x*256 + threadIdx.x; i<total; i += gridDim.x*256){
    int o = i % COUT;
    int r = i / COUT;
    int q = r % Nq;
    int b = r / Nq;
    int g = o / (COUT>>2);
    const float* sp = stats + ((size_t)(b*4+g))*16;
    float s=0.f, s2=0.f;
    #pragma unroll
    for (int nb=0;nb<8;++nb){ s += sp[nb*2]; s2 += sp[nb*2+1]; }
    float mean = s*invcnt;
    float var  = fmaxf(s2*invcnt - mean*mean, 0.f);
    float inv  = 1.0f / sqrtf(var + 1e-5f);
    float a  = gam[o] * inv;
    float bb = bet[o] - a*mean;
    const float* mp = mm + (size_t)i*2;
    float xv = (a>=0.f) ? mp[0] : mp[1];  // monotone affine: max commutes
    float v = fmaf(a, xv, bb);
    v = (v>=0.f) ? v : 0.2f*v;
    if (fo) fo[i]=v;
    if (outbase){
      int idx = outoff + ((b*COUT + o)*Nq + q);
      if (*flag) ((float*)outbase)[idx] = v;
      else       ((unsigned short*)outbase)[idx] = f2bf(v);
    }
  }
}

__global__ __launch_bounds__(256) void coor_kernel(
    const float* __restrict__ xyz2, void* __restrict__ outbase,
    const int* __restrict__ flag){
  int i = blockIdx.x*256+threadIdx.x;   // 32*3*128
  int m = i & 127;
  int c = (i>>7) % 3;
  int b = i / 384;
  float v = xyz2[((size_t)b*128+m)*3 + c];
  if (*flag) ((float*)outbase)[i] = v;
  else       ((unsigned short*)outbase)[i] = f2bf(v);
}

// ---------------------------------------------------------------------------
extern "C" void kernel_launch(void* const* d_in, const int* in_sizes, int n_in,
                              void* d_out, int out_size, void* d_ws, size_t ws_size,
                              hipStream_t stream){
  float* W    = (float*)d_ws;
  float* xyz0 = W;                      // 196608
  float* f0   = W + 196608;             // 524288
  float* f1   = W + 720896;             // 2097152
  float* xyz1 = W + 2818048;            // 49152
  float* f2   = W + 2867200;            // 1048576
  float* f3   = W + 3915776;            // 1048576
  float* xyz2 = W + 4964352;            // 12288
  float* stats= W + 4976640;            // 8192 (4 layers x 32 x 4 x 8buckets x 2)
  int*   flag = (int*)(W + 4984832);    // 16 (pad)
  float* PRM  = W + 4984848;            // 29792 canonical fp32 params
  int*  idx1  = (int*)(W + 5014640);    // 16384
  int*  idx2  = (int*)(W + 5031024);    // 4096
  float* SCR  = W + 5035120;            // aliased per-layer scratch
  int*   knnb = (int*)SCR;              // knn1: 1048576 ints
  int*   knnb2= knnb;                   // knn2: 262144 (after edge1 consumed knn1)
  int*   knnb3= knnb + 262144;          // knn3: 262144
  int*   knnb4= knnb + 524288;          // knn4: 65536
  float* mmb  = SCR + 1048576;          // <= 4194304 floats
  // total ~ 41.1 MB

  float* cw_in = PRM;          // 24
  float* cb_in = PRM+24;       // 8
  float* cw1 = PRM+32;   float* cg1 = PRM+544;   float* cbb1 = PRM+576;   // 512,32,32
  float* cw2 = PRM+608;  float* cg2 = PRM+4704;  float* cbb2 = PRM+4768;  // 4096,64,64
  float* cw3 = PRM+4832; float* cg3 = PRM+13024; float* cbb3 = PRM+13088; // 8192,64,64
  float* cw4 = PRM+13152;float* cg4 = PRM+29536; float* cbb4 = PRM+29664; // 16384,128,128

  detect_kernel<<<1,256,0,stream>>>((const unsigned short*)d_in[0], flag);

  PConv pc;
  const int psz[14] = {24,8,512,32,32,4096,64,64,8192,64,64,16384,128,128};
  float* pdst[14] = {cw_in,cb_in,cw1,cg1,cbb1,cw2,cg2,cbb2,cw3,cg3,cbb3,cw4,cg4,cbb4};
  for (int j=0;j<14;++j){ pc.s[j]=d_in[j+1]; pc.d[j]=pdst[j]; pc.sz[j]=psz[j]; }
  conv_params_kernel<<<117,256,0,stream>>>(pc, flag);

  prep_kernel<<<256,256,0,stream>>>(d_in[0], flag, cw_in, cb_in, xyz0, f0, stats);

  // ---- fused: FPS 2048->512 (32 blocks) || knn1 (1024 blocks)
  fused1_kernel<<<1056,256,0,stream>>>(xyz0, knnb, idx1, xyz1);

  // ---- layer 1: 2048q/2048k, 16 -> 32
  edge_kernel<8,32,16><<<dim3(128,32),256,0,stream>>>(f0, nullptr, knnb, cw1, mmb, stats+0, 2048, 2048);
  fin_kernel<<<1024,256,0,stream>>>(mmb, stats+0, cg1, cbb1, f1, nullptr, flag, 0, 2048, 32, 1.f/262144.f, 2097152);

  // ---- fused: FPS 512->128 (32) || knn2 (256) || knn3 (256)
  fused2_kernel<<<544,256,0,stream>>>(xyz0, xyz1, knnb2, knnb3, idx2, xyz2);

  // ---- layer 2: 512q/2048k, 64 -> 64 (queries gathered via idx1)
  edge_kernel<32,64,8><<<dim3(64,32),256,0,stream>>>(f1, idx1, knnb2, cw2, mmb, stats+2048, 512, 2048);
  fin_kernel<<<1024,256,0,stream>>>(mmb, stats+2048, cg2, cbb2, f2, nullptr, flag, 0, 512, 64, 1.f/131072.f, 1048576);

  // ---- layer 3: 512q/512k, 128 -> 64
  edge_kernel<64,64,8><<<dim3(64,32),256,0,stream>>>(f2, nullptr, knnb3, cw3, mmb, stats+4096, 512, 512);
  fin_kernel<<<1024,256,0,stream>>>(mmb, stats+4096, cg3, cbb3, f3, nullptr, flag, 0, 512, 64, 1.f/131072.f, 1048576);

  // ---- layer 4: 128q/512k, 128 -> 128 (queries via idx2) -> final f output
  knn_kernel<512,64><<<dim3(2,32),256,0,stream>>>(xyz2, xyz1, 128, knnb4);
  edge_kernel<64,128,4><<<dim3(32,32),256,0,stream>>>(f3, idx2, knnb4, cw4, mmb, stats+6144, 128, 512);
  fin_kernel<<<1024,256,0,stream>>>(mmb, stats+6144, cg4, cbb4, nullptr, d_out, flag, 12288, 128, 128, 1.f/65536.f, 524288);

  // ---- coor output (B,3,128)
  coor_kernel<<<48,256,0,stream>>>(xyz2, d_out, flag);
}

// Round 9
// 790.740 us; speedup vs baseline: 7.9938x; 1.0588x over previous
//
#include <hip/hip_runtime.h>
#include <hip/hip_bf16.h>

#define DEV __device__ __forceinline__

DEV float bf2f(unsigned short u){ return __uint_as_float(((unsigned)u)<<16); }
DEV unsigned short f2bf(float f){
  unsigned u = __float_as_uint(f);
  u += 0x7fffu + ((u>>16)&1u);   // RNE
  return (unsigned short)(u>>16);
}

// DPP-based u64 max step: permute both halves identically, umax with self as
// fallback (identity). ctrl: 0x110|N=row_shr:N, 0x142=row_bcast15, 0x143=row_bcast31.
template<int CTRL>
DEV unsigned long long dpp_umax(unsigned long long k){
  int lo = (int)(unsigned)k;
  int hi = (int)(unsigned)(k>>32);
  int plo = __builtin_amdgcn_update_dpp(lo, lo, CTRL, 0xF, 0xF, false);
  int phi = __builtin_amdgcn_update_dpp(hi, hi, CTRL, 0xF, 0xF, false);
  unsigned long long p = ((unsigned long long)(unsigned)phi << 32) | (unsigned)plo;
  return (p > k) ? p : k;
}

// ---------------------------------------------------------------------------
// dtype detection: genuine bf16 N(0,1) data never has exponent >= 0xC0;
// fp32 read as ushorts has ~25% such halfwords. flag=1 -> inputs fp32.
__global__ __launch_bounds__(256) void detect_kernel(
    const unsigned short* __restrict__ x, int* __restrict__ flag){
  __shared__ int cnt;
  if (threadIdx.x==0) cnt = 0;
  __syncthreads();
  int local = 0;
  for (int i=threadIdx.x; i<4096; i+=256){
    int e = (x[i]>>7)&0xFF;
    if (e >= 0xC0) local++;
  }
  atomicAdd(&cnt, local);
  __syncthreads();
  if (threadIdx.x==0) *flag = (cnt > 64) ? 1 : 0;
}

// ---------------------------------------------------------------------------
struct PConv {
  const void* s[14];
  float*      d[14];
  int         sz[14];
};
__global__ __launch_bounds__(256) void conv_params_kernel(PConv p, const int* __restrict__ flag){
  bool isf = (*flag != 0);
  int i = blockIdx.x*256 + threadIdx.x;
  int seg = 0, off = i;
  #pragma unroll
  for (seg=0; seg<14; ++seg){
    if (off < p.sz[seg]) break;
    off -= p.sz[seg];
  }
  if (seg >= 14) return;
  float v = isf ? ((const float*)p.s[seg])[off]
                : bf2f(((const unsigned short*)p.s[seg])[off]);
  p.d[seg][off] = v;
}

// ---------------------------------------------------------------------------
// prep: coords (B,3,2048)->(B,2048,3) fp32, f0 = w_in@x + b_in, zero stats(8192).
__global__ __launch_bounds__(256) void prep_kernel(
    const void* __restrict__ xraw, const int* __restrict__ flag,
    const float* __restrict__ w_in, const float* __restrict__ b_in,
    float* __restrict__ xyz0, float* __restrict__ f0, float* __restrict__ stats){
  int i = blockIdx.x*256 + threadIdx.x;          // 32*2048 threads
  if (i < 8192) stats[i] = 0.f;
  bool isf = (*flag != 0);
  int b = i >> 11, n = i & 2047;
  size_t base = (size_t)b*3*2048 + n;
  float X, Y, Z;
  if (isf){
    const float* xf = (const float*)xraw;
    X = xf[base]; Y = xf[base+2048]; Z = xf[base+4096];
  } else {
    const unsigned short* xu = (const unsigned short*)xraw;
    X = bf2f(xu[base]); Y = bf2f(xu[base+2048]); Z = bf2f(xu[base+4096]);
  }
  float* o3 = xyz0 + (size_t)i*3;
  o3[0]=X; o3[1]=Y; o3[2]=Z;
  float* fo = f0 + (size_t)i*8;
  #pragma unroll
  for (int o=0;o<8;++o){
    fo[o] = w_in[o*3+0]*X + w_in[o*3+1]*Y + w_in[o*3+2]*Z + b_in[o];
  }
}

// ---------------------------------------------------------------------------
// Split-K kNN body (256 threads): 4 threads/query, thread h scans m==h (mod 4),
// private sorted top-16 (strict-< insert => stable), leader 4-way lex merge.
// smem: >= max(NK*4, 130*QB) floats.
template<int NK, int QB>
DEV void knn_body(float* smem, const float* __restrict__ qxyz,
                  const float* __restrict__ kxyz, int Nq,
                  int* __restrict__ oidx, int bx, int b){
  float4* kd = (float4*)smem;
  int t = threadIdx.x;
  for (int i=t; i<NK; i+=256){
    const float* p = kxyz + ((size_t)b*NK + i)*3;
    float X=p[0], Y=p[1], Z=p[2];
    float sk = __fadd_rn(__fadd_rn(__fmul_rn(X,X),__fmul_rn(Y,Y)),__fmul_rn(Z,Z));
    kd[i] = make_float4(X,Y,Z,sk);
  }
  __syncthreads();
  int ql = t>>2, h = t&3;
  int q0 = bx*QB;
  const float* qp = qxyz + ((size_t)b*Nq + q0 + ql)*3;
  float QX=qp[0], QY=qp[1], QZ=qp[2];
  float sq = __fadd_rn(__fadd_rn(__fmul_rn(QX,QX),__fmul_rn(QY,QY)),__fmul_rn(QZ,QZ));
  float dl[16]; int il[16];
  #pragma unroll
  for (int j=0;j<16;++j){ dl[j]=3.4e38f; il[j]=-1; }
  for (int i=0; i<NK/4; i+=8){
    float d[8];
    #pragma unroll
    for (int u=0;u<8;++u){
      float4 c = kd[4*(i+u)+h];
      float dot = __fadd_rn(__fadd_rn(__fmul_rn(QX,c.x),__fmul_rn(QY,c.y)),__fmul_rn(QZ,c.z));
      d[u] = __fsub_rn(__fadd_rn(sq, c.w), __fmul_rn(2.0f,dot));
    }
    float dmin = fminf(fminf(fminf(d[0],d[1]),fminf(d[2],d[3])),
                       fminf(fminf(d[4],d[5]),fminf(d[6],d[7])));
    if (dmin < dl[15]){
      #pragma unroll
      for (int u=0;u<8;++u){
        float du = d[u];
        if (du < dl[15]){               // strict <: equal dist keeps earlier index
          dl[15]=du; il[15]=4*(i+u)+h;
          #pragma unroll
          for (int s=15;s>0;--s){
            if (dl[s] < dl[s-1]){       // strict <: stable among equals
              float td=dl[s]; dl[s]=dl[s-1]; dl[s-1]=td;
              int   ti=il[s]; il[s]=il[s-1]; il[s-1]=ti;
            }
          }
        }
      }
    }
  }
  __syncthreads();                       // kd reads done; reuse smem for lists
  float* dbuf = smem;
  int*   ibuf = (int*)(smem + QB*65);
  int base = ql*65 + h*16;
  #pragma unroll
  for (int j=0;j<16;++j){ dbuf[base+j]=dl[j]; ibuf[base+j]=il[j]; }
  __syncthreads();
  if (t < QB){
    const float* db = dbuf + t*65;
    const int*   ib = ibuf + t*65;
    int p0=0,p1=0,p2=0,p3=0;
    int* op = oidx + ((size_t)b*Nq + q0 + t)*16;
    #pragma unroll 1
    for (int j=0;j<16;++j){
      float e0 = (p0<16)? db[p0]    : 3.5e38f; int i0 = (p0<16)? ib[p0]    : 0x7fffffff;
      float e1 = (p1<16)? db[16+p1] : 3.5e38f; int i1 = (p1<16)? ib[16+p1] : 0x7fffffff;
      float e2 = (p2<16)? db[32+p2] : 3.5e38f; int i2 = (p2<16)? ib[32+p2] : 0x7fffffff;
      float e3 = (p3<16)? db[48+p3] : 3.5e38f; int i3 = (p3<16)? ib[48+p3] : 0x7fffffff;
      float bd=e0; int bi=i0; int bh=0;
      if (e1<bd || (e1==bd && i1<bi)){ bd=e1; bi=i1; bh=1; }
      if (e2<bd || (e2==bd && i2<bi)){ bd=e2; bi=i2; bh=2; }
      if (e3<bd || (e3==bd && i3<bi)){ bd=e3; bi=i3; bh=3; }
      op[j]=bi;
      p0 += (bh==0); p1 += (bh==1); p2 += (bh==2); p3 += (bh==3);
    }
  }
  __syncthreads();                       // safe smem handoff (fused callers)
}

// ---------------------------------------------------------------------------
// FPS body (256 threads, 4 waves, one barrier/step). Packed u64 argmax key
// (fbits(dist)<<32)|(~idx): umax == lex (dist desc, idx asc) == ref tie-break.
// Wave reduce = DPP row_shr/row_bcast chain (pure VALU, no LDS shuffles) to
// lane 63, readlane -> uniform wave key. Winner coords carried through the
// scan, so the unique matching lane posts (key,xyz) and the cross-wave merge
// yields Bi AND the centroid -- no dependent LDS broadcast at step top.
// smem: NP*4 + 48 + G floats. Exact fp32 no-FMA math.
template<int NP,int G>
DEV void fps_body(float* smem, const float* __restrict__ xyz,
                  int* __restrict__ oidx, float* __restrict__ oxyz, int b){
  constexpr int PPT = NP/256;
  float4* xl4 = (float4*)smem;
  unsigned long long* candK = (unsigned long long*)(smem + NP*4);   // [8] (2 par x 4 waves)
  float4* candX = (float4*)(smem + NP*4 + 16);                      // [8]
  int* selidx = (int*)(smem + NP*4 + 48);                           // [G]
  int t = threadIdx.x, w = t>>6;
  float px[PPT], py[PPT], pz[PPT], dist[PPT];
  #pragma unroll
  for (int j=0;j<PPT;++j){
    int gi = t + j*256;
    const float* p = xyz + ((size_t)b*NP + gi)*3;
    float X=p[0], Y=p[1], Z=p[2];
    px[j]=X; py[j]=Y; pz[j]=Z; dist[j]=1e10f;
    xl4[gi] = make_float4(X,Y,Z,0.f);
  }
  if (t==0) selidx[0] = 0;
  __syncthreads();
  float4 c0 = xl4[0];
  float cx=c0.x, cy=c0.y, cz=c0.z;
  int Bi = 0;
  for (int g=1; g<G; ++g){
    float bv=-1.f; int bi=0; float bxc=0.f, byc=0.f, bzc=0.f;
    #pragma unroll
    for (int j=0;j<PPT;++j){
      float dx=__fsub_rn(px[j],cx), dy=__fsub_rn(py[j],cy), dz=__fsub_rn(pz[j],cz);
      float d = __fadd_rn(__fadd_rn(__fmul_rn(dx,dx),__fmul_rn(dy,dy)),__fmul_rn(dz,dz));
      float nd = fminf(dist[j], d);
      dist[j] = nd;
      bool cc = (nd > bv);               // ascending idx in-lane: first-max kept
      bv = cc ? nd : bv;
      bi = cc ? (t + j*256) : bi;
      bxc = cc ? px[j] : bxc; byc = cc ? py[j] : byc; bzc = cc ? pz[j] : bzc;
    }
    unsigned long long klocal =
        ((unsigned long long)__float_as_uint(bv) << 32) | (unsigned)(0xFFFFFFFFu - bi);
    unsigned long long k = klocal;
    k = dpp_umax<0x111>(k);              // row_shr:1
    k = dpp_umax<0x112>(k);              // row_shr:2
    k = dpp_umax<0x114>(k);              // row_shr:4
    k = dpp_umax<0x118>(k);              // row_shr:8
    k = dpp_umax<0x142>(k);              // row_bcast15
    k = dpp_umax<0x143>(k);              // row_bcast31 -> lane 63 has wave max
    unsigned klo = (unsigned)__builtin_amdgcn_readlane((int)(unsigned)k, 63);
    unsigned khi = (unsigned)__builtin_amdgcn_readlane((int)(unsigned)(k>>32), 63);
    unsigned long long wkey = ((unsigned long long)khi<<32) | klo;
    int par = g & 1;
    if (klocal == wkey){                 // exactly one lane per wave (idx in key)
      candK[par*4 + w] = wkey;
      candX[par*4 + w] = make_float4(bxc, byc, bzc, 0.f);
    }
    __syncthreads();
    unsigned long long kk = candK[par*4+0]; float4 xx = candX[par*4+0];
    unsigned long long k1 = candK[par*4+1]; float4 x1 = candX[par*4+1];
    if (k1 > kk){ kk=k1; xx=x1; }
    unsigned long long k2 = candK[par*4+2]; float4 x2 = candX[par*4+2];
    if (k2 > kk){ kk=k2; xx=x2; }
    unsigned long long k3 = candK[par*4+3]; float4 x3 = candX[par*4+3];
    if (k3 > kk){ kk=k3; xx=x3; }
    Bi = (int)(0xFFFFFFFFu - (unsigned)kk);
    cx = xx.x; cy = xx.y; cz = xx.z;
    if (t==0) selidx[g] = Bi;
  }
  __syncthreads();
  for (int i=t; i<G; i+=256){
    int s = selidx[i];
    float4 c = xl4[s];
    oidx[(size_t)b*G + i] = s;
    float* op = oxyz + ((size_t)b*G + i)*3;
    op[0]=c.x; op[1]=c.y; op[2]=c.z;
  }
}

// ---------------------------------------------------------------------------
// EdgeConv pre-norm body (256 threads). See round-3 notes; smem-pointer form
// so it can run inside fused kernels. smem floats: WTB + QB*ESTR + QB*CF + 8.
template<int CF,int COUT,int QB>
DEV void edge_body(float* smem, const float* __restrict__ fk,
                   const int* __restrict__ sel, const int* __restrict__ knn,
                   const float* __restrict__ w, float* __restrict__ mm,
                   float* __restrict__ stats, int Nq, int Nk, int bx, int b){
  constexpr int CIN = 2*CF;
  constexpr int GPQ = COUT/2;
  constexpr int WS  = COUT+1;
  constexpr int ESTR= CF*16+8;
  constexpr int WTB = ((CF*WS+3)&~3);
  static_assert(QB*GPQ == 256, "block mapping");
  float* wtb = smem;                  // CF*WS
  float* e   = smem + WTB;            // QB*ESTR (16B aligned)
  float* fqs = e + QB*ESTR;           // QB*CF
  float* sS  = fqs + QB*CF;           // 8
  int t = threadIdx.x;
  int q0 = bx*QB;

  if (t<8) sS[t]=0.f;
  for (int i=t; i<QB*CF; i+=256){
    int ql = i/CF, c = i&(CF-1);
    int qi = sel ? sel[b*Nq + q0 + ql] : (q0 + ql);
    fqs[i] = fk[((size_t)b*Nk + qi)*CF + c];
  }
  for (int i=t; i<CF*COUT; i+=256){
    int o = i/CIN, c = i - o*CIN;     // first half: c < CF
    // NOTE: stage half A directly from w[o*CIN + c], c in [0,CF)
    ;
  }
  // stage weight half A (c < CF)
  for (int i=t; i<CF*COUT; i+=256){
    int o = i/CF, c = i&(CF-1);
    wtb[c*WS+o] = w[o*CIN + c];
  }
  if (t < QB*16){
    int ql = t>>4, k = t&15;
    int nid = knn[((size_t)b*Nq + q0 + ql)*16 + k];
    const float4* row = (const float4*)(fk + ((size_t)b*Nk + nid)*CF);
    float* ep = e + ql*ESTR + k;
    #pragma unroll
    for (int c4=0; c4<CF/4; ++c4){
      float4 v = row[c4];
      ep[(c4*4+0)*16]=v.x; ep[(c4*4+1)*16]=v.y; ep[(c4*4+2)*16]=v.z; ep[(c4*4+3)*16]=v.w;
    }
  }
  __syncthreads();

  int ql = t/GPQ, o = t%GPQ;
  const float* eb = e + ql*ESTR;
  const float* fqb = fqs + ql*CF;
  float y0[16], y1[16];
  #pragma unroll
  for (int k=0;k<16;++k){ y0[k]=0.f; y1[k]=0.f; }
  float zA0=0.f, zA1=0.f;
  for (int c=0;c<CF;++c){
    float w0 = wtb[c*WS+o];
    float w1 = wtb[c*WS+o+GPQ];
    float fqc = fqb[c];
    zA0 = fmaf(w0,fqc,zA0); zA1 = fmaf(w1,fqc,zA1);
    const float4* ev4 = (const float4*)(eb + c*16);
    #pragma unroll
    for (int k4=0;k4<4;++k4){
      float4 ev = ev4[k4];
      y0[k4*4+0]=fmaf(w0,ev.x,y0[k4*4+0]); y0[k4*4+1]=fmaf(w0,ev.y,y0[k4*4+1]);
      y0[k4*4+2]=fmaf(w0,ev.z,y0[k4*4+2]); y0[k4*4+3]=fmaf(w0,ev.w,y0[k4*4+3]);
      y1[k4*4+0]=fmaf(w1,ev.x,y1[k4*4+0]); y1[k4*4+1]=fmaf(w1,ev.y,y1[k4*4+1]);
      y1[k4*4+2]=fmaf(w1,ev.z,y1[k4*4+2]); y1[k4*4+3]=fmaf(w1,ev.w,y1[k4*4+3]);
    }
  }
  __syncthreads();
  // stage weight half B (c >= CF)
  for (int i=t; i<CF*COUT; i+=256){
    int oo = i/CF, c = i&(CF-1);
    wtb[c*WS+oo] = w[oo*CIN + CF + c];
  }
  __syncthreads();
  float zB0=0.f, zB1=0.f;
  for (int c=0;c<CF;++c){
    float fqc = fqb[c];
    zB0 = fmaf(wtb[c*WS+o],fqc,zB0);
    zB1 = fmaf(wtb[c*WS+o+GPQ],fqc,zB1);
  }
  float z0 = zB0 - zA0, z1 = zB1 - zA1;

  float mx0=-3.4e38f, mn0=3.4e38f, s0=0.f, q0s=0.f;
  float mx1=-3.4e38f, mn1=3.4e38f, s1=0.f, q1s=0.f;
  #pragma unroll
  for (int k=0;k<16;++k){
    float v0 = y0[k]+z0, v1 = y1[k]+z1;
    mx0=fmaxf(mx0,v0); mn0=fminf(mn0,v0); s0+=v0; q0s=fmaf(v0,v0,q0s);
    mx1=fmaxf(mx1,v1); mn1=fminf(mn1,v1); s1+=v1; q1s=fmaf(v1,v1,q1s);
  }
  int g0 = o/(COUT/4);
  atomicAdd(&sS[g0],   s0); atomicAdd(&sS[4+g0],   q0s);
  atomicAdd(&sS[g0+2], s1); atomicAdd(&sS[6+g0],   q1s);
  size_t mi0 = ((size_t)b*Nq + q0 + ql)*COUT + o;
  ((float2*)mm)[mi0]       = make_float2(mx0,mn0);
  ((float2*)mm)[mi0+GPQ]   = make_float2(mx1,mn1);
  __syncthreads();
  if (t<8){
    int g = t>>1, which = t&1;
    float val = which ? sS[4+g] : sS[g];
    atomicAdd(&stats[(((size_t)b*4+g)*8 + (bx&7))*2 + which], val);
  }
}

// ---------------------------------------------------------------------------
// Fused launches: FPS blocks first (grab CU slots immediately); independent
// knn/edge work fills the rest. Events are banned -> only overlap path.
__global__ __launch_bounds__(256,4) void fused1_kernel(
    const float* __restrict__ xyz0, int* __restrict__ knnb1,
    int* __restrict__ idx1, float* __restrict__ xyz1){
  __shared__ __align__(16) float smem[8752];   // fps1 needs 8752; knn 8320
  int bx = blockIdx.x;
  if (bx < 32){
    fps_body<2048,512>(smem, xyz0, idx1, xyz1, bx);
  } else {
    int rid = bx - 32;                          // 1024 knn1 blocks
    knn_body<2048,64>(smem, xyz0, xyz0, 2048, knnb1, rid & 31, rid >> 5);
  }
}

__global__ __launch_bounds__(256,4) void fused2_kernel(
    const float* __restrict__ xyz0, const float* __restrict__ xyz1,
    const int* __restrict__ knnb1,
    int* __restrict__ knnb2, int* __restrict__ knnb3,
    int* __restrict__ idx2, float* __restrict__ xyz2,
    const float* __restrict__ f0, const float* __restrict__ cw1,
    float* __restrict__ mmb, float* __restrict__ stats1){
  __shared__ __align__(16) float smem[8320];   // knn 8320 > edge1 2576 > fps2 2224
  int bx = blockIdx.x;
  if (bx < 32){
    fps_body<512,128>(smem, xyz1, idx2, xyz2, bx);
  } else if (bx < 288){
    int rid = bx - 32;                          // 256 knn2 blocks
    knn_body<2048,64>(smem, xyz1, xyz0, 512, knnb2, rid & 7, rid >> 3);
  } else if (bx < 544){
    int rid = bx - 288;                         // 256 knn3 blocks
    knn_body<512,64>(smem, xyz1, xyz1, 512, knnb3, rid & 7, rid >> 3);
  } else {
    int rid = bx - 544;                         // 4096 edge1 blocks
    edge_body<8,32,16>(smem, f0, nullptr, knnb1, cw1, mmb, stats1,
                       2048, 2048, rid & 127, rid >> 7);
  }
}

template<int NK,int QB>
__global__ __launch_bounds__(QB*4,4) void knn_kernel(
    const float* __restrict__ qxyz, const float* __restrict__ kxyz,
    int Nq, int* __restrict__ oidx){
  constexpr int SM = (NK*4 > 130*QB) ? NK*4 : 130*QB;
  __shared__ __align__(16) float smem[SM];
  knn_body<NK,QB>(smem, qxyz, kxyz, Nq, oidx, blockIdx.x, blockIdx.y);
}

template<int CF,int COUT,int QB>
__global__ __launch_bounds__(256) void edge_kernel(
    const float* __restrict__ fk, const int* __restrict__ sel,
    const int* __restrict__ knn, const float* __restrict__ w,
    float* __restrict__ mm, float* __restrict__ stats, int Nq, int Nk){
  constexpr int WS  = COUT+1;
  constexpr int ESTR= CF*16+8;
  constexpr int WTB = ((CF*WS+3)&~3);
  constexpr int SM  = WTB + QB*ESTR + QB*CF + 8;
  __shared__ __align__(16) float smem[SM];
  edge_body<CF,COUT,QB>(smem, fk, sel, knn, w, mm, stats, Nq, Nk,
                        blockIdx.x, blockIdx.y);
}

// ---------------------------------------------------------------------------
// finalize: sum stat buckets, GN affine on max (min if a<0) + LeakyReLU.
__global__ __launch_bounds__(256) void fin_kernel(
    const float* __restrict__ mm, const float* __restrict__ stats,
    const float* __restrict__ gam, const float* __restrict__ bet,
    float* __restrict__ fo, void* __restrict__ outbase, const int* __restrict__ flag,
    int outoff, int Nq, int COUT, float invcnt, int total){
  for (int i = blockIdx.x*256 + threadIdx.x; i<total; i += gridDim.x*256){
    int o = i % COUT;
    int r = i / COUT;
    int q = r % Nq;
    int b = r / Nq;
    int g = o / (COUT>>2);
    const float* sp = stats + ((size_t)(b*4+g))*16;
    float s=0.f, s2=0.f;
    #pragma unroll
    for (int nb=0;nb<8;++nb){ s += sp[nb*2]; s2 += sp[nb*2+1]; }
    float mean = s*invcnt;
    float var  = fmaxf(s2*invcnt - mean*mean, 0.f);
    float inv  = 1.0f / sqrtf(var + 1e-5f);
    float a  = gam[o] * inv;
    float bb = bet[o] - a*mean;
    const float* mp = mm + (size_t)i*2;
    float xv = (a>=0.f) ? mp[0] : mp[1];  // monotone affine: max commutes
    float v = fmaf(a, xv, bb);
    v = (v>=0.f) ? v : 0.2f*v;
    if (fo) fo[i]=v;
    if (outbase){
      int idx = outoff + ((b*COUT + o)*Nq + q);
      if (*flag) ((float*)outbase)[idx] = v;
      else       ((unsigned short*)outbase)[idx] = f2bf(v);
    }
  }
}

__global__ __launch_bounds__(256) void coor_kernel(
    const float* __restrict__ xyz2, void* __restrict__ outbase,
    const int* __restrict__ flag){
  int i = blockIdx.x*256+threadIdx.x;   // 32*3*128
  int m = i & 127;
  int c = (i>>7) % 3;
  int b = i / 384;
  float v = xyz2[((size_t)b*128+m)*3 + c];
  if (*flag) ((float*)outbase)[i] = v;
  else       ((unsigned short*)outbase)[i] = f2bf(v);
}

// ---------------------------------------------------------------------------
extern "C" void kernel_launch(void* const* d_in, const int* in_sizes, int n_in,
                              void* d_out, int out_size, void* d_ws, size_t ws_size,
                              hipStream_t stream){
  float* W    = (float*)d_ws;
  float* xyz0 = W;                      // 196608
  float* f0   = W + 196608;             // 524288
  float* f1   = W + 720896;             // 2097152
  float* xyz1 = W + 2818048;            // 49152
  float* f2   = W + 2867200;            // 1048576
  float* f3   = W + 3915776;            // 1048576
  float* xyz2 = W + 4964352;            // 12288
  float* stats= W + 4976640;            // 8192 (4 layers x 32 x 4 x 8buckets x 2)
  int*   flag = (int*)(W + 4984832);    // 16 (pad)
  float* PRM  = W + 4984848;            // 29792 canonical fp32 params
  int*  idx1  = (int*)(W + 5014640);    // 16384
  int*  idx2  = (int*)(W + 5031024);    // 4096
  float* SCR  = W + 5035120;            // aliased per-layer scratch
  int*   knnb = (int*)SCR;              // knn1: 1048576 ints (dead after fused2)
  int*   knnb4= (int*)SCR;              // knn4 reuses knn1 region (65536 ints)
  int*   knnb2= (int*)f3;               // knn2: 262144 ints in f3 (dead at fin3)
  int*   knnb3= (int*)f3 + 262144;      // knn3: 262144 ints in f3
  float* mmb  = SCR + 1048576;          // <= 4194304 floats
  // total ~ 41.1 MB (unchanged)

  float* cw_in = PRM;          // 24
  float* cb_in = PRM+24;       // 8
  float* cw1 = PRM+32;   float* cg1 = PRM+544;   float* cbb1 = PRM+576;   // 512,32,32
  float* cw2 = PRM+608;  float* cg2 = PRM+4704;  float* cbb2 = PRM+4768;  // 4096,64,64
  float* cw3 = PRM+4832; float* cg3 = PRM+13024; float* cbb3 = PRM+13088; // 8192,64,64
  float* cw4 = PRM+13152;float* cg4 = PRM+29536; float* cbb4 = PRM+29664; // 16384,128,128

  detect_kernel<<<1,256,0,stream>>>((const unsigned short*)d_in[0], flag);

  PConv pc;
  const int psz[14] = {24,8,512,32,32,4096,64,64,8192,64,64,16384,128,128};
  float* pdst[14] = {cw_in,cb_in,cw1,cg1,cbb1,cw2,cg2,cbb2,cw3,cg3,cbb3,cw4,cg4,cbb4};
  for (int j=0;j<14;++j){ pc.s[j]=d_in[j+1]; pc.d[j]=pdst[j]; pc.sz[j]=psz[j]; }
  conv_params_kernel<<<117,256,0,stream>>>(pc, flag);

  prep_kernel<<<256,256,0,stream>>>(d_in[0], flag, cw_in, cb_in, xyz0, f0, stats);

  // ---- fused1: FPS 2048->512 (32 blocks) || knn1 (1024 blocks)
  fused1_kernel<<<1056,256,0,stream>>>(xyz0, knnb, idx1, xyz1);

  // ---- fused2: FPS 512->128 (32) || knn2 (256) || knn3 (256) || edge1 (4096)
  fused2_kernel<<<4640,256,0,stream>>>(xyz0, xyz1, knnb, knnb2, knnb3,
                                       idx2, xyz2, f0, cw1, mmb, stats+0);

  // ---- layer 1 finalize
  fin_kernel<<<1024,256,0,stream>>>(mmb, stats+0, cg1, cbb1, f1, nullptr, flag, 0, 2048, 32, 1.f/262144.f, 2097152);

  // ---- layer 2: 512q/2048k, 64 -> 64 (queries gathered via idx1)
  edge_kernel<32,64,8><<<dim3(64,32),256,0,stream>>>(f1, idx1, knnb2, cw2, mmb, stats+2048, 512, 2048);
  fin_kernel<<<1024,256,0,stream>>>(mmb, stats+2048, cg2, cbb2, f2, nullptr, flag, 0, 512, 64, 1.f/131072.f, 1048576);

  // ---- layer 3: 512q/512k, 128 -> 64
  edge_kernel<64,64,8><<<dim3(64,32),256,0,stream>>>(f2, nullptr, knnb3, cw3, mmb, stats+4096, 512, 512);
  fin_kernel<<<1024,256,0,stream>>>(mmb, stats+4096, cg3, cbb3, f3, nullptr, flag, 0, 512, 64, 1.f/131072.f, 1048576);

  // ---- layer 4: 128q/512k, 128 -> 128 (queries via idx2) -> final f output
  knn_kernel<512,64><<<dim3(2,32),256,0,stream>>>(xyz2, xyz1, 128, knnb4);
  edge_kernel<64,128,4><<<dim3(32,32),256,0,stream>>>(f3, idx2, knnb4, cw4, mmb, stats+6144, 128, 512);
  fin_kernel<<<1024,256,0,stream>>>(mmb, stats+6144, cg4, cbb4, nullptr, d_out, flag, 12288, 128, 128, 1.f/65536.f, 524288);

  // ---- coor output (B,3,128)
  coor_kernel<<<48,256,0,stream>>>(xyz2, d_out, flag);
}